// Round 1
// baseline (5426.167 us; speedup 1.0000x reference)
//
#include <hip/hip_runtime.h>
#include <math.h>

#define Nn 50000
#define Ee 800000
#define FIN 128
#define HIDd 64
#define NH 4
#define HD 256
#define NEG 0.2f
#define BEPS 1e-5f

static __device__ __forceinline__ float lrelu(float x) { return x > 0.f ? x : NEG * x; }

// ---------------- utility fills ----------------
__global__ void fill_kernel(float* __restrict__ p, float v, int n) {
  int i = blockIdx.x * 256 + threadIdx.x;
  if (i < n) p[i] = v;
}

__global__ void init_bias_kernel(float* __restrict__ p, const float* __restrict__ b, int n) {
  int i = blockIdx.x * 256 + threadIdx.x;
  if (i < n) p[i] = b[i & (HD - 1)];
}

// ---------------- GEMM: C[M,256] = A[M,K] @ B[K,256] ----------------
__global__ __launch_bounds__(256) void gemm_kernel(const float* __restrict__ A,
                                                   const float* __restrict__ B,
                                                   float* __restrict__ Cout,
                                                   int M, int K) {
  __shared__ float As[16][64];
  __shared__ float Bs[16][64];
  const int tid = threadIdx.x;
  const int tx = tid & 15, ty = tid >> 4;
  const int m0 = blockIdx.x * 64, n0 = blockIdx.y * 64;
  const int ar = tid >> 2, ak = (tid & 3) * 4;
  const int br = tid >> 4, bn = (tid & 15) * 4;
  float acc[4][4] = {{0.f}};
  for (int k0 = 0; k0 < K; k0 += 16) {
    float4 av = make_float4(0.f, 0.f, 0.f, 0.f);
    if (m0 + ar < M) av = *(const float4*)(A + (size_t)(m0 + ar) * K + k0 + ak);
    As[ak + 0][ar] = av.x; As[ak + 1][ar] = av.y; As[ak + 2][ar] = av.z; As[ak + 3][ar] = av.w;
    *(float4*)&Bs[br][bn] = *(const float4*)(B + (size_t)(k0 + br) * 256 + n0 + bn);
    __syncthreads();
#pragma unroll
    for (int kk = 0; kk < 16; kk++) {
      float4 a4 = *(const float4*)&As[kk][ty * 4];
      float4 b4 = *(const float4*)&Bs[kk][tx * 4];
      float a_[4] = {a4.x, a4.y, a4.z, a4.w};
      float b_[4] = {b4.x, b4.y, b4.z, b4.w};
#pragma unroll
      for (int i = 0; i < 4; i++)
#pragma unroll
        for (int j = 0; j < 4; j++) acc[i][j] += a_[i] * b_[j];
    }
    __syncthreads();
  }
#pragma unroll
  for (int i = 0; i < 4; i++) {
    int r = m0 + ty * 4 + i;
    if (r < M)
      *(float4*)(Cout + (size_t)r * 256 + n0 + tx * 4) =
          make_float4(acc[i][0], acc[i][1], acc[i][2], acc[i][3]);
  }
}

// ---------------- alpha_src / alpha_dst: wave per (node, head) ----------------
__global__ __launch_bounds__(256) void alpha_kernel(const float* __restrict__ h,
                                                    const float* __restrict__ a_s,
                                                    const float* __restrict__ a_d,
                                                    float* __restrict__ asrc,
                                                    float* __restrict__ adst) {
  int wid = blockIdx.x * 4 + (threadIdx.x >> 6);
  int lane = threadIdx.x & 63;
  if (wid >= Nn * NH) return;
  int n = wid >> 2, hh = wid & 3;
  float hv = h[(size_t)n * HD + hh * HIDd + lane];
  float vs = hv * a_s[hh * HIDd + lane];
  float vd = hv * a_d[hh * HIDd + lane];
#pragma unroll
  for (int off = 32; off > 0; off >>= 1) {
    vs += __shfl_down(vs, off);
    vd += __shfl_down(vd, off);
  }
  if (lane == 0) { asrc[wid] = vs; adst[wid] = vd; }
}

// ---------------- attention: segment max / denom / scatter ----------------
static __device__ __forceinline__ void atomic_max_f(float* a, float v) {
  if (v >= 0.f) atomicMax((int*)a, __float_as_int(v));
  else          atomicMin((unsigned int*)a, __float_as_uint(v));
}

__global__ void att_max_kernel(const int* __restrict__ src, const int* __restrict__ dst,
                               const float* __restrict__ asrc, const float* __restrict__ adst,
                               float* __restrict__ mbuf) {
  int i = blockIdx.x * 256 + threadIdx.x;
  if (i >= Ee + Nn) return;
  int s, d;
  if (i < Ee) { s = src[i]; d = dst[i]; } else { s = d = i - Ee; }
  float4 av = *(const float4*)(asrc + (size_t)s * 4);
  float4 dv = *(const float4*)(adst + (size_t)d * 4);
  atomic_max_f(&mbuf[d * 4 + 0], lrelu(av.x + dv.x));
  atomic_max_f(&mbuf[d * 4 + 1], lrelu(av.y + dv.y));
  atomic_max_f(&mbuf[d * 4 + 2], lrelu(av.z + dv.z));
  atomic_max_f(&mbuf[d * 4 + 3], lrelu(av.w + dv.w));
}

__global__ void att_den_kernel(const int* __restrict__ src, const int* __restrict__ dst,
                               const float* __restrict__ asrc, const float* __restrict__ adst,
                               const float* __restrict__ mbuf, float* __restrict__ den) {
  int i = blockIdx.x * 256 + threadIdx.x;
  if (i >= Ee + Nn) return;
  int s, d;
  if (i < Ee) { s = src[i]; d = dst[i]; } else { s = d = i - Ee; }
  float4 av = *(const float4*)(asrc + (size_t)s * 4);
  float4 dv = *(const float4*)(adst + (size_t)d * 4);
  float4 mv = *(const float4*)(mbuf + (size_t)d * 4);
  atomicAdd(&den[d * 4 + 0], expf(lrelu(av.x + dv.x) - mv.x));
  atomicAdd(&den[d * 4 + 1], expf(lrelu(av.y + dv.y) - mv.y));
  atomicAdd(&den[d * 4 + 2], expf(lrelu(av.z + dv.z) - mv.z));
  atomicAdd(&den[d * 4 + 3], expf(lrelu(av.w + dv.w) - mv.w));
}

__global__ __launch_bounds__(256) void att_scatter_kernel(
    const int* __restrict__ src, const int* __restrict__ dst,
    const float* __restrict__ hfeat, const float* __restrict__ asrc,
    const float* __restrict__ adst, const float* __restrict__ mbuf,
    const float* __restrict__ den, float* __restrict__ agg) {
  int wid = blockIdx.x * 4 + (threadIdx.x >> 6);
  int lane = threadIdx.x & 63;
  if (wid >= (Ee + Nn) * 4) return;
  int i = wid >> 2, hh = wid & 3;
  int s, d;
  if (i < Ee) { s = src[i]; d = dst[i]; } else { s = d = i - Ee; }
  float e = lrelu(asrc[s * 4 + hh] + adst[d * 4 + hh]);
  float att = expf(e - mbuf[d * 4 + hh]) / den[d * 4 + hh];
  float v = hfeat[(size_t)s * HD + hh * HIDd + lane] * att;
  atomicAdd(&agg[(size_t)d * HD + hh * HIDd + lane], v);
}

// ---------------- layer-2 head mean ----------------
__global__ void mean_heads_kernel(const float* __restrict__ agg, const float* __restrict__ b,
                                  float* __restrict__ h2) {
  int i = blockIdx.x * 256 + threadIdx.x;
  if (i >= Nn * HIDd) return;
  int n = i >> 6, dd = i & 63;
  const float* r = agg + (size_t)n * HD + dd;
  h2[i] = 0.25f * (r[0] + r[64] + r[128] + r[192]) + b[dd];
}

// ---------------- BatchNorm ----------------
__global__ void bn_stats_kernel(const float* __restrict__ x, float* __restrict__ stats,
                                int nrows, int C) {
  int r0 = blockIdx.x * 128;
  int tpc = 256 / C;
  int c = threadIdx.x % C;
  int ro = threadIdx.x / C;
  int rend = min(r0 + 128, nrows);
  float s = 0.f, s2 = 0.f;
  for (int r = r0 + ro; r < rend; r += tpc) {
    float v = x[(size_t)r * C + c];
    s += v; s2 += v * v;
  }
  atomicAdd(&stats[c], s);
  atomicAdd(&stats[C + c], s2);
}

__global__ void bn_apply_kernel(float* __restrict__ x, const float* __restrict__ stats,
                                const float* __restrict__ g, const float* __restrict__ be,
                                int C, int do_lrelu) {
  int i = blockIdx.x * 256 + threadIdx.x;
  if (i >= Nn * C) return;
  int c = i % C;
  float mu = stats[c] * (1.f / Nn);
  float var = stats[C + c] * (1.f / Nn) - mu * mu;
  float y = (x[i] - mu) * rsqrtf(var + BEPS) * g[c] + be[c];
  x[i] = do_lrelu ? lrelu(y) : y;
}

// ---------------- Edge MLP: [hs,hd,|hs-hd|,attr] -> 128 -> 64 -> 1 ----------------
#define NGROUP 50000  // Ee / 16
__global__ __launch_bounds__(256) void edge_mlp_kernel(
    const float* __restrict__ hn, const int* __restrict__ src, const int* __restrict__ dst,
    const float* __restrict__ eattr,
    const float* __restrict__ Wm1, const float* __restrict__ bm1,
    const float* __restrict__ Wm2, const float* __restrict__ bm2,
    const float* __restrict__ Wm3, const float* __restrict__ bm3,
    float* __restrict__ out) {
  __shared__ float w1c[64 * 128];   // one 64-row chunk of Wm1
  __shared__ float efs[16][196];    // 16 edges x 193 features (padded)
  __shared__ float t1s[16][128];
  const int tid = threadIdx.x;
  const int es = tid >> 4;   // edge slot 0..15
  const int l = tid & 15;    // 0..15
  for (int g = blockIdx.x; g < NGROUP; g += gridDim.x) {
    int e = g * 16 + es;
    __syncthreads();
    {
      int s = src[e], d = dst[e];
      float4 a = *(const float4*)(hn + (size_t)s * 64 + 4 * l);
      float4 b = *(const float4*)(hn + (size_t)d * 64 + 4 * l);
      *(float4*)&efs[es][4 * l] = a;
      *(float4*)&efs[es][64 + 4 * l] = b;
      *(float4*)&efs[es][128 + 4 * l] =
          make_float4(fabsf(a.x - b.x), fabsf(a.y - b.y), fabsf(a.z - b.z), fabsf(a.w - b.w));
      if (l == 0) efs[es][192] = eattr[e];
    }
    // thread computes t1 channels [4l..4l+3] and [64+4l..64+4l+3]
    float4 acc0 = make_float4(0.f, 0.f, 0.f, 0.f);
    float4 acc1 = make_float4(0.f, 0.f, 0.f, 0.f);
    for (int c = 0; c < 3; c++) {
      __syncthreads();
      const float4* s4 = (const float4*)(Wm1 + (size_t)c * 64 * 128);
      float4* d4 = (float4*)w1c;
#pragma unroll
      for (int i = 0; i < 8; i++) d4[tid + i * 256] = s4[tid + i * 256];
      __syncthreads();
#pragma unroll 8
      for (int kk = 0; kk < 64; kk++) {
        float efv = efs[es][c * 64 + kk];
        float4 wa = *(const float4*)&w1c[kk * 128 + l * 4];
        float4 wb = *(const float4*)&w1c[kk * 128 + 64 + l * 4];
        acc0.x += efv * wa.x; acc0.y += efv * wa.y; acc0.z += efv * wa.z; acc0.w += efv * wa.w;
        acc1.x += efv * wb.x; acc1.y += efv * wb.y; acc1.z += efv * wb.z; acc1.w += efv * wb.w;
      }
    }
    {
      float efv = efs[es][192];
      float4 wa = *(const float4*)(Wm1 + 192 * 128 + l * 4);
      float4 wb = *(const float4*)(Wm1 + 192 * 128 + 64 + l * 4);
      acc0.x += efv * wa.x; acc0.y += efv * wa.y; acc0.z += efv * wa.z; acc0.w += efv * wa.w;
      acc1.x += efv * wb.x; acc1.y += efv * wb.y; acc1.z += efv * wb.z; acc1.w += efv * wb.w;
    }
    float4 ba = *(const float4*)(bm1 + l * 4);
    float4 bb = *(const float4*)(bm1 + 64 + l * 4);
    float4 t1a, t1b;
    t1a.x = lrelu(acc0.x + ba.x); t1a.y = lrelu(acc0.y + ba.y);
    t1a.z = lrelu(acc0.z + ba.z); t1a.w = lrelu(acc0.w + ba.w);
    t1b.x = lrelu(acc1.x + bb.x); t1b.y = lrelu(acc1.y + bb.y);
    t1b.z = lrelu(acc1.z + bb.z); t1b.w = lrelu(acc1.w + bb.w);
    *(float4*)&t1s[es][l * 4] = t1a;
    *(float4*)&t1s[es][64 + l * 4] = t1b;
    __syncthreads();
    // MLP2: thread computes out channels [4l..4l+3]
    float4 acc2 = *(const float4*)(bm2 + l * 4);
#pragma unroll 8
    for (int k = 0; k < 128; k++) {
      float t1k = t1s[es][k];
      float4 wv = *(const float4*)(Wm2 + (size_t)k * 64 + l * 4);
      acc2.x += t1k * wv.x; acc2.y += t1k * wv.y; acc2.z += t1k * wv.z; acc2.w += t1k * wv.w;
    }
    float4 w3v = *(const float4*)(Wm3 + l * 4);
    float part = lrelu(acc2.x) * w3v.x + lrelu(acc2.y) * w3v.y +
                 lrelu(acc2.z) * w3v.z + lrelu(acc2.w) * w3v.w;
    part += __shfl_down(part, 8, 16);
    part += __shfl_down(part, 4, 16);
    part += __shfl_down(part, 2, 16);
    part += __shfl_down(part, 1, 16);
    if (l == 0) out[e] = part + bm3[0];
  }
}

// ---------------- orchestration ----------------
extern "C" void kernel_launch(void* const* d_in, const int* in_sizes, int n_in,
                              void* d_out, int out_size, void* d_ws, size_t ws_size,
                              hipStream_t stream) {
  const float* x    = (const float*)d_in[0];
  const int*   ei   = (const int*)d_in[1];
  const float* eatt = (const float*)d_in[2];
  const float* W0 = (const float*)d_in[3];
  const float* as0 = (const float*)d_in[4];
  const float* ad0 = (const float*)d_in[5];
  const float* b0 = (const float*)d_in[6];
  const float* W1 = (const float*)d_in[7];
  const float* as1 = (const float*)d_in[8];
  const float* ad1 = (const float*)d_in[9];
  const float* b1 = (const float*)d_in[10];
  const float* W2 = (const float*)d_in[11];
  const float* as2 = (const float*)d_in[12];
  const float* ad2 = (const float*)d_in[13];
  const float* b2 = (const float*)d_in[14];
  const float* g0 = (const float*)d_in[15];
  const float* be0 = (const float*)d_in[16];
  const float* g1 = (const float*)d_in[17];
  const float* be1 = (const float*)d_in[18];
  const float* g2 = (const float*)d_in[19];
  const float* be2 = (const float*)d_in[20];
  const float* Wm1 = (const float*)d_in[21];
  const float* bm1 = (const float*)d_in[22];
  const float* Wm2 = (const float*)d_in[23];
  const float* bm2 = (const float*)d_in[24];
  const float* Wm3 = (const float*)d_in[25];
  const float* bm3 = (const float*)d_in[26];
  const int* src = ei;
  const int* dst = ei + Ee;
  float* out = (float*)d_out;

  float* ws = (float*)d_ws;
  float* h     = ws;                          // N*HD
  float* agg   = h + (size_t)Nn * HD;         // N*HD
  float* asrc  = agg + (size_t)Nn * HD;       // N*4
  float* adst  = asrc + (size_t)Nn * 4;       // N*4
  float* mbuf  = adst + (size_t)Nn * 4;       // N*4
  float* den   = mbuf + (size_t)Nn * 4;       // N*4
  float* h2    = den + (size_t)Nn * 4;        // N*64
  float* stats = h2 + (size_t)Nn * HIDd;      // 512

  auto gat = [&](const float* xin, int K, const float* W, const float* a_s, const float* a_d,
                 const float* bias, bool concat) {
    gemm_kernel<<<dim3((Nn + 63) / 64, 4), 256, 0, stream>>>(xin, W, h, Nn, K);
    alpha_kernel<<<(Nn * NH + 3) / 4, 256, 0, stream>>>(h, a_s, a_d, asrc, adst);
    fill_kernel<<<(Nn * 4 + 255) / 256, 256, 0, stream>>>(mbuf, -INFINITY, Nn * 4);
    fill_kernel<<<(Nn * 4 + 255) / 256, 256, 0, stream>>>(den, 0.f, Nn * 4);
    if (concat)
      init_bias_kernel<<<(Nn * HD + 255) / 256, 256, 0, stream>>>(agg, bias, Nn * HD);
    else
      fill_kernel<<<(Nn * HD + 255) / 256, 256, 0, stream>>>(agg, 0.f, Nn * HD);
    att_max_kernel<<<(Ee + Nn + 255) / 256, 256, 0, stream>>>(src, dst, asrc, adst, mbuf);
    att_den_kernel<<<(Ee + Nn + 255) / 256, 256, 0, stream>>>(src, dst, asrc, adst, mbuf, den);
    att_scatter_kernel<<<Ee + Nn, 256, 0, stream>>>(src, dst, h, asrc, adst, mbuf, den, agg);
  };

  // Layer 0
  gat(x, FIN, W0, as0, ad0, b0, true);
  fill_kernel<<<2, 256, 0, stream>>>(stats, 0.f, 512);
  bn_stats_kernel<<<(Nn + 127) / 128, 256, 0, stream>>>(agg, stats, Nn, HD);
  bn_apply_kernel<<<(Nn * HD + 255) / 256, 256, 0, stream>>>(agg, stats, g0, be0, HD, 1);
  // Layer 1
  gat(agg, HD, W1, as1, ad1, b1, true);
  fill_kernel<<<2, 256, 0, stream>>>(stats, 0.f, 512);
  bn_stats_kernel<<<(Nn + 127) / 128, 256, 0, stream>>>(agg, stats, Nn, HD);
  bn_apply_kernel<<<(Nn * HD + 255) / 256, 256, 0, stream>>>(agg, stats, g1, be1, HD, 1);
  // Layer 2 (concat=False)
  gat(agg, HD, W2, as2, ad2, b2, false);
  mean_heads_kernel<<<(Nn * HIDd + 255) / 256, 256, 0, stream>>>(agg, b2, h2);
  fill_kernel<<<1, 256, 0, stream>>>(stats, 0.f, 128);
  bn_stats_kernel<<<(Nn + 127) / 128, 256, 0, stream>>>(h2, stats, Nn, HIDd);
  bn_apply_kernel<<<(Nn * HIDd + 255) / 256, 256, 0, stream>>>(h2, stats, g2, be2, HIDd, 0);
  // Edge MLP
  edge_mlp_kernel<<<768, 256, 0, stream>>>(h2, src, dst, eatt, Wm1, bm1, Wm2, bm2, Wm3, bm3, out);
}

// Round 2
// 2981.074 us; speedup vs baseline: 1.8202x; 1.8202x over previous
//
#include <hip/hip_runtime.h>
#include <math.h>

#define Nn 50000
#define Ee 800000
#define FIN 128
#define HIDd 64
#define NH 4
#define HD 256
#define NEG 0.2f
#define BEPS 1e-5f

static __device__ __forceinline__ float lrelu(float x) { return x > 0.f ? x : NEG * x; }

// ---------------- utility fills ----------------
__global__ void fill_kernel(float* __restrict__ p, float v, int n) {
  int i = blockIdx.x * 256 + threadIdx.x;
  if (i < n) p[i] = v;
}

__global__ void filli_kernel(int* __restrict__ p, int v, int n) {
  int i = blockIdx.x * 256 + threadIdx.x;
  if (i < n) p[i] = v;
}

// ---------------- CSR build (edge_index is layer-invariant: build once) ----------------
__global__ void hist_kernel(const int* __restrict__ dst, int* __restrict__ deg) {
  int i = blockIdx.x * 256 + threadIdx.x;
  if (i < Ee) atomicAdd(&deg[dst[i]], 1);
}

// one block, 1024 threads: exclusive scan of deg[0..Nn) -> rowstart[0..Nn]
__global__ __launch_bounds__(1024) void scan_kernel(const int* __restrict__ deg,
                                                    int* __restrict__ rowstart) {
  __shared__ int ts[1024];
  const int tid = threadIdx.x;
  const int CH = (Nn + 1023) / 1024;
  const int base = tid * CH;
  int s = 0;
  for (int j = 0; j < CH; j++) {
    int idx = base + j;
    if (idx < Nn) s += deg[idx];
  }
  ts[tid] = s;
  __syncthreads();
  for (int off = 1; off < 1024; off <<= 1) {
    int v = (tid >= off) ? ts[tid - off] : 0;
    __syncthreads();
    ts[tid] += v;
    __syncthreads();
  }
  int run = (tid == 0) ? 0 : ts[tid - 1];
  for (int j = 0; j < CH; j++) {
    int idx = base + j;
    if (idx < Nn) {
      rowstart[idx] = run;
      run += deg[idx];
      if (idx == Nn - 1) rowstart[Nn] = run;
    }
  }
}

__global__ void cursor_init_kernel(const int* __restrict__ rowstart, int* __restrict__ cursor) {
  int i = blockIdx.x * 256 + threadIdx.x;
  if (i < Nn) cursor[i] = rowstart[i];
}

__global__ void elist_fill_kernel(const int* __restrict__ src, const int* __restrict__ dst,
                                  int* __restrict__ cursor, int* __restrict__ elist) {
  int i = blockIdx.x * 256 + threadIdx.x;
  if (i >= Ee + Nn) return;
  int s, d;
  if (i < Ee) { s = src[i]; d = dst[i]; } else { s = d = i - Ee; }
  int pos = atomicAdd(&cursor[d], 1);
  elist[pos] = s;
}

// ---------------- GEMM: C[M,256] = A[M,K] @ B[K,256] ----------------
__global__ __launch_bounds__(256) void gemm_kernel(const float* __restrict__ A,
                                                   const float* __restrict__ B,
                                                   float* __restrict__ Cout,
                                                   int M, int K) {
  __shared__ float As[16][64];
  __shared__ float Bs[16][64];
  const int tid = threadIdx.x;
  const int tx = tid & 15, ty = tid >> 4;
  const int m0 = blockIdx.x * 64, n0 = blockIdx.y * 64;
  const int ar = tid >> 2, ak = (tid & 3) * 4;
  const int br = tid >> 4, bn = (tid & 15) * 4;
  float acc[4][4] = {{0.f}};
  for (int k0 = 0; k0 < K; k0 += 16) {
    float4 av = make_float4(0.f, 0.f, 0.f, 0.f);
    if (m0 + ar < M) av = *(const float4*)(A + (size_t)(m0 + ar) * K + k0 + ak);
    As[ak + 0][ar] = av.x; As[ak + 1][ar] = av.y; As[ak + 2][ar] = av.z; As[ak + 3][ar] = av.w;
    *(float4*)&Bs[br][bn] = *(const float4*)(B + (size_t)(k0 + br) * 256 + n0 + bn);
    __syncthreads();
#pragma unroll
    for (int kk = 0; kk < 16; kk++) {
      float4 a4 = *(const float4*)&As[kk][ty * 4];
      float4 b4 = *(const float4*)&Bs[kk][tx * 4];
      float a_[4] = {a4.x, a4.y, a4.z, a4.w};
      float b_[4] = {b4.x, b4.y, b4.z, b4.w};
#pragma unroll
      for (int i = 0; i < 4; i++)
#pragma unroll
        for (int j = 0; j < 4; j++) acc[i][j] += a_[i] * b_[j];
    }
    __syncthreads();
  }
#pragma unroll
  for (int i = 0; i < 4; i++) {
    int r = m0 + ty * 4 + i;
    if (r < M)
      *(float4*)(Cout + (size_t)r * 256 + n0 + tx * 4) =
          make_float4(acc[i][0], acc[i][1], acc[i][2], acc[i][3]);
  }
}

// ---------------- alpha_src / alpha_dst: wave per (node, head) ----------------
__global__ __launch_bounds__(256) void alpha_kernel(const float* __restrict__ h,
                                                    const float* __restrict__ a_s,
                                                    const float* __restrict__ a_d,
                                                    float* __restrict__ asrc,
                                                    float* __restrict__ adst) {
  int wid = blockIdx.x * 4 + (threadIdx.x >> 6);
  int lane = threadIdx.x & 63;
  if (wid >= Nn * NH) return;
  int n = wid >> 2, hh = wid & 3;
  float hv = h[(size_t)n * HD + hh * HIDd + lane];
  float vs = hv * a_s[hh * HIDd + lane];
  float vd = hv * a_d[hh * HIDd + lane];
#pragma unroll
  for (int off = 32; off > 0; off >>= 1) {
    vs += __shfl_down(vs, off);
    vd += __shfl_down(vd, off);
  }
  if (lane == 0) { asrc[wid] = vs; adst[wid] = vd; }
}

// ---------------- fused attention gather: block per node, wave per head ----------------
__global__ __launch_bounds__(256) void gat_gather_kernel(
    const int* __restrict__ elist, const int* __restrict__ rowstart,
    const float* __restrict__ h, const float* __restrict__ asrc,
    const float* __restrict__ adst, const float* __restrict__ bias,
    float* __restrict__ agg, int concat) {
  const int n = blockIdx.x;
  const int hh = threadIdx.x >> 6;
  const int lane = threadIdx.x & 63;
  const int start = rowstart[n], end = rowstart[n + 1];
  const float adstv = adst[n * 4 + hh];
  // pass 1: segment max (lane-parallel over edges)
  float m = -INFINITY;
  for (int j = start + lane; j < end; j += 64)
    m = fmaxf(m, lrelu(asrc[elist[j] * 4 + hh] + adstv));
#pragma unroll
  for (int off = 32; off > 0; off >>= 1) m = fmaxf(m, __shfl_xor(m, off));
  // pass 2: chunked exp + weighted accumulation
  float acc = 0.f, den = 0.f;
  for (int c = start; c < end; c += 64) {
    int cl = min(64, end - c);
    float w = 0.f;
    int sidx = 0;
    if (lane < cl) {
      sidx = elist[c + lane];
      w = expf(lrelu(asrc[sidx * 4 + hh] + adstv) - m);
    }
    den += w;
    for (int j = 0; j < cl; j++) {
      float wj = __shfl(w, j);
      int sj = __shfl(sidx, j);
      acc += wj * h[(size_t)sj * HD + hh * HIDd + lane];
    }
  }
#pragma unroll
  for (int off = 32; off > 0; off >>= 1) den += __shfl_xor(den, off);
  float o = acc / den;
  if (concat) o += bias[hh * HIDd + lane];
  agg[(size_t)n * HD + hh * HIDd + lane] = o;
}

// ---------------- layer-2 head mean ----------------
__global__ void mean_heads_kernel(const float* __restrict__ agg, const float* __restrict__ b,
                                  float* __restrict__ h2) {
  int i = blockIdx.x * 256 + threadIdx.x;
  if (i >= Nn * HIDd) return;
  int n = i >> 6, dd = i & 63;
  const float* r = agg + (size_t)n * HD + dd;
  h2[i] = 0.25f * (r[0] + r[64] + r[128] + r[192]) + b[dd];
}

// ---------------- BatchNorm ----------------
__global__ void bn_stats_kernel(const float* __restrict__ x, float* __restrict__ stats,
                                int nrows, int C) {
  int r0 = blockIdx.x * 128;
  int tpc = 256 / C;
  int c = threadIdx.x % C;
  int ro = threadIdx.x / C;
  int rend = min(r0 + 128, nrows);
  float s = 0.f, s2 = 0.f;
  for (int r = r0 + ro; r < rend; r += tpc) {
    float v = x[(size_t)r * C + c];
    s += v; s2 += v * v;
  }
  atomicAdd(&stats[c], s);
  atomicAdd(&stats[C + c], s2);
}

__global__ void bn_apply_kernel(float* __restrict__ x, const float* __restrict__ stats,
                                const float* __restrict__ g, const float* __restrict__ be,
                                int C, int do_lrelu) {
  int i = blockIdx.x * 256 + threadIdx.x;
  if (i >= Nn * C) return;
  int c = i % C;
  float mu = stats[c] * (1.f / Nn);
  float var = stats[C + c] * (1.f / Nn) - mu * mu;
  float y = (x[i] - mu) * rsqrtf(var + BEPS) * g[c] + be[c];
  x[i] = do_lrelu ? lrelu(y) : y;
}

// ---------------- Edge MLP: [hs,hd,|hs-hd|,attr] -> 128 -> 64 -> 1 ----------------
#define NGROUP 50000  // Ee / 16
__global__ __launch_bounds__(256) void edge_mlp_kernel(
    const float* __restrict__ hn, const int* __restrict__ src, const int* __restrict__ dst,
    const float* __restrict__ eattr,
    const float* __restrict__ Wm1, const float* __restrict__ bm1,
    const float* __restrict__ Wm2, const float* __restrict__ bm2,
    const float* __restrict__ Wm3, const float* __restrict__ bm3,
    float* __restrict__ out) {
  __shared__ float w1c[64 * 128];   // one 64-row chunk of Wm1
  __shared__ float efs[16][196];    // 16 edges x 193 features (padded)
  __shared__ float t1s[16][128];
  const int tid = threadIdx.x;
  const int es = tid >> 4;   // edge slot 0..15
  const int l = tid & 15;    // 0..15
  for (int g = blockIdx.x; g < NGROUP; g += gridDim.x) {
    int e = g * 16 + es;
    __syncthreads();
    {
      int s = src[e], d = dst[e];
      float4 a = *(const float4*)(hn + (size_t)s * 64 + 4 * l);
      float4 b = *(const float4*)(hn + (size_t)d * 64 + 4 * l);
      *(float4*)&efs[es][4 * l] = a;
      *(float4*)&efs[es][64 + 4 * l] = b;
      *(float4*)&efs[es][128 + 4 * l] =
          make_float4(fabsf(a.x - b.x), fabsf(a.y - b.y), fabsf(a.z - b.z), fabsf(a.w - b.w));
      if (l == 0) efs[es][192] = eattr[e];
    }
    float4 acc0 = make_float4(0.f, 0.f, 0.f, 0.f);
    float4 acc1 = make_float4(0.f, 0.f, 0.f, 0.f);
    for (int c = 0; c < 3; c++) {
      __syncthreads();
      const float4* s4 = (const float4*)(Wm1 + (size_t)c * 64 * 128);
      float4* d4 = (float4*)w1c;
#pragma unroll
      for (int i = 0; i < 8; i++) d4[tid + i * 256] = s4[tid + i * 256];
      __syncthreads();
#pragma unroll 8
      for (int kk = 0; kk < 64; kk++) {
        float efv = efs[es][c * 64 + kk];
        float4 wa = *(const float4*)&w1c[kk * 128 + l * 4];
        float4 wb = *(const float4*)&w1c[kk * 128 + 64 + l * 4];
        acc0.x += efv * wa.x; acc0.y += efv * wa.y; acc0.z += efv * wa.z; acc0.w += efv * wa.w;
        acc1.x += efv * wb.x; acc1.y += efv * wb.y; acc1.z += efv * wb.z; acc1.w += efv * wb.w;
      }
    }
    {
      float efv = efs[es][192];
      float4 wa = *(const float4*)(Wm1 + 192 * 128 + l * 4);
      float4 wb = *(const float4*)(Wm1 + 192 * 128 + 64 + l * 4);
      acc0.x += efv * wa.x; acc0.y += efv * wa.y; acc0.z += efv * wa.z; acc0.w += efv * wa.w;
      acc1.x += efv * wb.x; acc1.y += efv * wb.y; acc1.z += efv * wb.z; acc1.w += efv * wb.w;
    }
    float4 ba = *(const float4*)(bm1 + l * 4);
    float4 bb = *(const float4*)(bm1 + 64 + l * 4);
    float4 t1a, t1b;
    t1a.x = lrelu(acc0.x + ba.x); t1a.y = lrelu(acc0.y + ba.y);
    t1a.z = lrelu(acc0.z + ba.z); t1a.w = lrelu(acc0.w + ba.w);
    t1b.x = lrelu(acc1.x + bb.x); t1b.y = lrelu(acc1.y + bb.y);
    t1b.z = lrelu(acc1.z + bb.z); t1b.w = lrelu(acc1.w + bb.w);
    *(float4*)&t1s[es][l * 4] = t1a;
    *(float4*)&t1s[es][64 + l * 4] = t1b;
    __syncthreads();
    float4 acc2 = *(const float4*)(bm2 + l * 4);
#pragma unroll 8
    for (int k = 0; k < 128; k++) {
      float t1k = t1s[es][k];
      float4 wv = *(const float4*)(Wm2 + (size_t)k * 64 + l * 4);
      acc2.x += t1k * wv.x; acc2.y += t1k * wv.y; acc2.z += t1k * wv.z; acc2.w += t1k * wv.w;
    }
    float4 w3v = *(const float4*)(Wm3 + l * 4);
    float part = lrelu(acc2.x) * w3v.x + lrelu(acc2.y) * w3v.y +
                 lrelu(acc2.z) * w3v.z + lrelu(acc2.w) * w3v.w;
    part += __shfl_down(part, 8, 16);
    part += __shfl_down(part, 4, 16);
    part += __shfl_down(part, 2, 16);
    part += __shfl_down(part, 1, 16);
    if (l == 0) out[e] = part + bm3[0];
  }
}

// ---------------- orchestration ----------------
extern "C" void kernel_launch(void* const* d_in, const int* in_sizes, int n_in,
                              void* d_out, int out_size, void* d_ws, size_t ws_size,
                              hipStream_t stream) {
  const float* x    = (const float*)d_in[0];
  const int*   ei   = (const int*)d_in[1];
  const float* eatt = (const float*)d_in[2];
  const float* W0 = (const float*)d_in[3];
  const float* as0 = (const float*)d_in[4];
  const float* ad0 = (const float*)d_in[5];
  const float* b0 = (const float*)d_in[6];
  const float* W1 = (const float*)d_in[7];
  const float* as1 = (const float*)d_in[8];
  const float* ad1 = (const float*)d_in[9];
  const float* b1 = (const float*)d_in[10];
  const float* W2 = (const float*)d_in[11];
  const float* as2 = (const float*)d_in[12];
  const float* ad2 = (const float*)d_in[13];
  const float* b2 = (const float*)d_in[14];
  const float* g0 = (const float*)d_in[15];
  const float* be0 = (const float*)d_in[16];
  const float* g1 = (const float*)d_in[17];
  const float* be1 = (const float*)d_in[18];
  const float* g2 = (const float*)d_in[19];
  const float* be2 = (const float*)d_in[20];
  const float* Wm1 = (const float*)d_in[21];
  const float* bm1 = (const float*)d_in[22];
  const float* Wm2 = (const float*)d_in[23];
  const float* bm2 = (const float*)d_in[24];
  const float* Wm3 = (const float*)d_in[25];
  const float* bm3 = (const float*)d_in[26];
  const int* src = ei;
  const int* dst = ei + Ee;
  float* out = (float*)d_out;

  float* ws = (float*)d_ws;
  float* h     = ws;                          // N*HD
  float* agg   = h + (size_t)Nn * HD;         // N*HD
  float* asrc  = agg + (size_t)Nn * HD;       // N*4
  float* adst  = asrc + (size_t)Nn * 4;       // N*4
  float* h2    = adst + (size_t)Nn * 4;       // N*64
  float* stats = h2 + (size_t)Nn * HIDd;      // 512
  int* deg      = (int*)(stats + 512);        // N
  int* rowstart = deg + Nn;                   // N+1
  int* cursor   = rowstart + Nn + 1;          // N
  int* elist    = cursor + Nn;                // E+N

  // ---- CSR build (once; edge_index identical for all 3 layers) ----
  filli_kernel<<<(Nn + 255) / 256, 256, 0, stream>>>(deg, 1, Nn);  // self loops
  hist_kernel<<<(Ee + 255) / 256, 256, 0, stream>>>(dst, deg);
  scan_kernel<<<1, 1024, 0, stream>>>(deg, rowstart);
  cursor_init_kernel<<<(Nn + 255) / 256, 256, 0, stream>>>(rowstart, cursor);
  elist_fill_kernel<<<(Ee + Nn + 255) / 256, 256, 0, stream>>>(src, dst, cursor, elist);

  auto gat = [&](const float* xin, int K, const float* W, const float* a_s, const float* a_d,
                 const float* bias, bool concat) {
    gemm_kernel<<<dim3((Nn + 63) / 64, 4), 256, 0, stream>>>(xin, W, h, Nn, K);
    alpha_kernel<<<(Nn * NH + 3) / 4, 256, 0, stream>>>(h, a_s, a_d, asrc, adst);
    gat_gather_kernel<<<Nn, 256, 0, stream>>>(elist, rowstart, h, asrc, adst, bias, agg,
                                              concat ? 1 : 0);
  };

  // Layer 0
  gat(x, FIN, W0, as0, ad0, b0, true);
  fill_kernel<<<2, 256, 0, stream>>>(stats, 0.f, 512);
  bn_stats_kernel<<<(Nn + 127) / 128, 256, 0, stream>>>(agg, stats, Nn, HD);
  bn_apply_kernel<<<(Nn * HD + 255) / 256, 256, 0, stream>>>(agg, stats, g0, be0, HD, 1);
  // Layer 1
  gat(agg, HD, W1, as1, ad1, b1, true);
  fill_kernel<<<2, 256, 0, stream>>>(stats, 0.f, 512);
  bn_stats_kernel<<<(Nn + 127) / 128, 256, 0, stream>>>(agg, stats, Nn, HD);
  bn_apply_kernel<<<(Nn * HD + 255) / 256, 256, 0, stream>>>(agg, stats, g1, be1, HD, 1);
  // Layer 2 (concat=False)
  gat(agg, HD, W2, as2, ad2, b2, false);
  mean_heads_kernel<<<(Nn * HIDd + 255) / 256, 256, 0, stream>>>(agg, b2, h2);
  fill_kernel<<<1, 256, 0, stream>>>(stats, 0.f, 128);
  bn_stats_kernel<<<(Nn + 127) / 128, 256, 0, stream>>>(h2, stats, Nn, HIDd);
  bn_apply_kernel<<<(Nn * HIDd + 255) / 256, 256, 0, stream>>>(h2, stats, g2, be2, HIDd, 0);
  // Edge MLP
  edge_mlp_kernel<<<768, 256, 0, stream>>>(h2, src, dst, eatt, Wm1, bm1, Wm2, bm2, Wm3, bm3, out);
}

// Round 3
// 1594.981 us; speedup vs baseline: 3.4020x; 1.8690x over previous
//
#include <hip/hip_runtime.h>
#include <math.h>

#define Nn 50000
#define Ee 800000
#define FIN 128
#define HIDd 64
#define NH 4
#define HD 256
#define NEG 0.2f
#define BEPS 1e-5f

typedef __attribute__((ext_vector_type(8))) short short8;
typedef __attribute__((ext_vector_type(4))) float f32x4;
typedef unsigned int uint;
typedef unsigned short ushort;

static __device__ __forceinline__ float lrelu(float x) { return x > 0.f ? x : NEG * x; }
static __device__ __forceinline__ float bf2f(short x) {
  return __uint_as_float(((uint)(ushort)x) << 16);
}
static __device__ __forceinline__ ushort f2bf(float f) {
  uint u = __float_as_uint(f);
  return (ushort)((u + 0x7FFF + ((u >> 16) & 1)) >> 16);
}

// ---------------- utility fills ----------------
__global__ void fill_kernel(float* __restrict__ p, float v, int n) {
  int i = blockIdx.x * 256 + threadIdx.x;
  if (i < n) p[i] = v;
}

__global__ void filli_kernel(int* __restrict__ p, int v, int n) {
  int i = blockIdx.x * 256 + threadIdx.x;
  if (i < n) p[i] = v;
}

// ---------------- CSR build (edge_index is layer-invariant: build once) ----------------
__global__ void hist_kernel(const int* __restrict__ dst, int* __restrict__ deg) {
  int i = blockIdx.x * 256 + threadIdx.x;
  if (i < Ee) atomicAdd(&deg[dst[i]], 1);
}

__global__ __launch_bounds__(1024) void scan_kernel(const int* __restrict__ deg,
                                                    int* __restrict__ rowstart) {
  __shared__ int ts[1024];
  const int tid = threadIdx.x;
  const int CH = (Nn + 1023) / 1024;
  const int base = tid * CH;
  int s = 0;
  for (int j = 0; j < CH; j++) {
    int idx = base + j;
    if (idx < Nn) s += deg[idx];
  }
  ts[tid] = s;
  __syncthreads();
  for (int off = 1; off < 1024; off <<= 1) {
    int v = (tid >= off) ? ts[tid - off] : 0;
    __syncthreads();
    ts[tid] += v;
    __syncthreads();
  }
  int run = (tid == 0) ? 0 : ts[tid - 1];
  for (int j = 0; j < CH; j++) {
    int idx = base + j;
    if (idx < Nn) {
      rowstart[idx] = run;
      run += deg[idx];
      if (idx == Nn - 1) rowstart[Nn] = run;
    }
  }
}

__global__ void cursor_init_kernel(const int* __restrict__ rowstart, int* __restrict__ cursor) {
  int i = blockIdx.x * 256 + threadIdx.x;
  if (i < Nn) cursor[i] = rowstart[i];
}

__global__ void elist_fill_kernel(const int* __restrict__ src, const int* __restrict__ dst,
                                  int* __restrict__ cursor, int* __restrict__ elist) {
  int i = blockIdx.x * 256 + threadIdx.x;
  if (i >= Ee + Nn) return;
  int s, d;
  if (i < Ee) { s = src[i]; d = dst[i]; } else { s = d = i - Ee; }
  int pos = atomicAdd(&cursor[d], 1);
  elist[pos] = s;
}

// ---------------- GEMM: C[M,256] = A[M,K] @ B[K,256] (fp32 VALU) ----------------
__global__ __launch_bounds__(256) void gemm_kernel(const float* __restrict__ A,
                                                   const float* __restrict__ B,
                                                   float* __restrict__ Cout,
                                                   int M, int K) {
  __shared__ float As[16][64];
  __shared__ float Bs[16][64];
  const int tid = threadIdx.x;
  const int tx = tid & 15, ty = tid >> 4;
  const int m0 = blockIdx.x * 64, n0 = blockIdx.y * 64;
  const int ar = tid >> 2, ak = (tid & 3) * 4;
  const int br = tid >> 4, bn = (tid & 15) * 4;
  float acc[4][4] = {{0.f}};
  for (int k0 = 0; k0 < K; k0 += 16) {
    float4 av = make_float4(0.f, 0.f, 0.f, 0.f);
    if (m0 + ar < M) av = *(const float4*)(A + (size_t)(m0 + ar) * K + k0 + ak);
    As[ak + 0][ar] = av.x; As[ak + 1][ar] = av.y; As[ak + 2][ar] = av.z; As[ak + 3][ar] = av.w;
    *(float4*)&Bs[br][bn] = *(const float4*)(B + (size_t)(k0 + br) * 256 + n0 + bn);
    __syncthreads();
#pragma unroll
    for (int kk = 0; kk < 16; kk++) {
      float4 a4 = *(const float4*)&As[kk][ty * 4];
      float4 b4 = *(const float4*)&Bs[kk][tx * 4];
      float a_[4] = {a4.x, a4.y, a4.z, a4.w};
      float b_[4] = {b4.x, b4.y, b4.z, b4.w};
#pragma unroll
      for (int i = 0; i < 4; i++)
#pragma unroll
        for (int j = 0; j < 4; j++) acc[i][j] += a_[i] * b_[j];
    }
    __syncthreads();
  }
#pragma unroll
  for (int i = 0; i < 4; i++) {
    int r = m0 + ty * 4 + i;
    if (r < M)
      *(float4*)(Cout + (size_t)r * 256 + n0 + tx * 4) =
          make_float4(acc[i][0], acc[i][1], acc[i][2], acc[i][3]);
  }
}

// ---------------- alpha_src / alpha_dst: wave per (node, head) ----------------
__global__ __launch_bounds__(256) void alpha_kernel(const float* __restrict__ h,
                                                    const float* __restrict__ a_s,
                                                    const float* __restrict__ a_d,
                                                    float* __restrict__ asrc,
                                                    float* __restrict__ adst) {
  int wid = blockIdx.x * 4 + (threadIdx.x >> 6);
  int lane = threadIdx.x & 63;
  if (wid >= Nn * NH) return;
  int n = wid >> 2, hh = wid & 3;
  float hv = h[(size_t)n * HD + hh * HIDd + lane];
  float vs = hv * a_s[hh * HIDd + lane];
  float vd = hv * a_d[hh * HIDd + lane];
#pragma unroll
  for (int off = 32; off > 0; off >>= 1) {
    vs += __shfl_down(vs, off);
    vd += __shfl_down(vd, off);
  }
  if (lane == 0) { asrc[wid] = vs; adst[wid] = vd; }
}

// ---------------- fused attention gather: block per node, wave per head ----------------
__global__ __launch_bounds__(256) void gat_gather_kernel(
    const int* __restrict__ elist, const int* __restrict__ rowstart,
    const float* __restrict__ h, const float* __restrict__ asrc,
    const float* __restrict__ adst, const float* __restrict__ bias,
    float* __restrict__ agg, int concat) {
  const int n = blockIdx.x;
  const int hh = threadIdx.x >> 6;
  const int lane = threadIdx.x & 63;
  const int start = rowstart[n], end = rowstart[n + 1];
  const float adstv = adst[n * 4 + hh];
  float m = -INFINITY;
  for (int j = start + lane; j < end; j += 64)
    m = fmaxf(m, lrelu(asrc[elist[j] * 4 + hh] + adstv));
#pragma unroll
  for (int off = 32; off > 0; off >>= 1) m = fmaxf(m, __shfl_xor(m, off));
  float acc = 0.f, den = 0.f;
  for (int c = start; c < end; c += 64) {
    int cl = min(64, end - c);
    float w = 0.f;
    int sidx = 0;
    if (lane < cl) {
      sidx = elist[c + lane];
      w = expf(lrelu(asrc[sidx * 4 + hh] + adstv) - m);
    }
    den += w;
    for (int j = 0; j < cl; j++) {
      float wj = __shfl(w, j);
      int sj = __shfl(sidx, j);
      acc += wj * h[(size_t)sj * HD + hh * HIDd + lane];
    }
  }
#pragma unroll
  for (int off = 32; off > 0; off >>= 1) den += __shfl_xor(den, off);
  float o = acc / den;
  if (concat) o += bias[hh * HIDd + lane];
  agg[(size_t)n * HD + hh * HIDd + lane] = o;
}

// ---------------- layer-2 head mean ----------------
__global__ void mean_heads_kernel(const float* __restrict__ agg, const float* __restrict__ b,
                                  float* __restrict__ h2) {
  int i = blockIdx.x * 256 + threadIdx.x;
  if (i >= Nn * HIDd) return;
  int n = i >> 6, dd = i & 63;
  const float* r = agg + (size_t)n * HD + dd;
  h2[i] = 0.25f * (r[0] + r[64] + r[128] + r[192]) + b[dd];
}

// ---------------- BatchNorm ----------------
__global__ void bn_stats_kernel(const float* __restrict__ x, float* __restrict__ stats,
                                int nrows, int C) {
  int r0 = blockIdx.x * 128;
  int tpc = 256 / C;
  int c = threadIdx.x % C;
  int ro = threadIdx.x / C;
  int rend = min(r0 + 128, nrows);
  float s = 0.f, s2 = 0.f;
  for (int r = r0 + ro; r < rend; r += tpc) {
    float v = x[(size_t)r * C + c];
    s += v; s2 += v * v;
  }
  atomicAdd(&stats[c], s);
  atomicAdd(&stats[C + c], s2);
}

__global__ void bn_apply_kernel(float* __restrict__ x, const float* __restrict__ stats,
                                const float* __restrict__ g, const float* __restrict__ be,
                                int C, int do_lrelu) {
  int i = blockIdx.x * 256 + threadIdx.x;
  if (i >= Nn * C) return;
  int c = i % C;
  float mu = stats[c] * (1.f / Nn);
  float var = stats[C + c] * (1.f / Nn) - mu * mu;
  float y = (x[i] - mu) * rsqrtf(var + BEPS) * g[c] + be[c];
  x[i] = do_lrelu ? lrelu(y) : y;
}

// ---------------- bf16 prep kernels ----------------
__global__ void cvt_bf16_kernel(const float* __restrict__ in, ushort* __restrict__ out, int n) {
  int i = blockIdx.x * 256 + threadIdx.x;
  if (i < n) out[i] = f2bf(in[i]);
}

// Wm1[193,128] -> B-frag-major bf16, K padded to 224: [(chunk*8+tile)*64+lane]*8+j
__global__ void w1frag_kernel(const float* __restrict__ Wm1, ushort* __restrict__ W1f) {
  int idx = blockIdx.x * 256 + threadIdx.x;
  if (idx >= 7 * 8 * 64 * 8) return;
  int j = idx & 7, lane = (idx >> 3) & 63, tile = (idx >> 9) & 7, chunk = idx >> 12;
  int n = tile * 16 + (lane & 15);
  int k = chunk * 32 + (lane >> 4) * 8 + j;
  W1f[idx] = (k < 193) ? f2bf(Wm1[k * 128 + n]) : (ushort)0;
}

// Wm2[128,64] -> B-frag-major bf16: [(chunk*4+tile)*64+lane]*8+j
__global__ void w2frag_kernel(const float* __restrict__ Wm2, ushort* __restrict__ W2f) {
  int idx = blockIdx.x * 256 + threadIdx.x;
  if (idx >= 4 * 4 * 64 * 8) return;
  int j = idx & 7, lane = (idx >> 3) & 63, tile = (idx >> 9) & 3, chunk = idx >> 11;
  int n = tile * 16 + (lane & 15);
  int k = chunk * 32 + (lane >> 4) * 8 + j;
  W2f[idx] = f2bf(Wm2[k * 64 + n]);
}

// ---------------- Edge MLP via MFMA: [hs,hd,|hs-hd|,attr](224 pad) ->128 ->64 ->1 ----------------
static __device__ __forceinline__ short8 absdiff8(short8 a, short8 b) {
  short8 r;
#pragma unroll
  for (int j = 0; j < 8; j++) r[j] = (short)f2bf(fabsf(bf2f(a[j]) - bf2f(b[j])));
  return r;
}

#define MLP1_STEP(c, e0x, e1x)                                                         \
  {                                                                                    \
    short8 _a0 = (e0x);                                                                \
    short8 _a1 = (e1x);                                                                \
    const uint4* bp = (const uint4*)W1f + (c) * 512 + lane;                            \
    _Pragma("unroll") for (int t = 0; t < 8; t++) {                                    \
      uint4 braw = bp[t * 64];                                                         \
      short8 b = *(short8*)&braw;                                                      \
      acc0[t] = __builtin_amdgcn_mfma_f32_16x16x32_bf16(_a0, b, acc0[t], 0, 0, 0);     \
      acc1[t] = __builtin_amdgcn_mfma_f32_16x16x32_bf16(_a1, b, acc1[t], 0, 0, 0);     \
    }                                                                                  \
  }

__global__ __launch_bounds__(256) void edge_mlp_mfma_kernel(
    const ushort* __restrict__ hb, const int* __restrict__ src, const int* __restrict__ dst,
    const float* __restrict__ eattr, const ushort* __restrict__ W1f,
    const ushort* __restrict__ W2f, const float* __restrict__ bm1,
    const float* __restrict__ bm2, const float* __restrict__ Wm3,
    const float* __restrict__ bm3, float* __restrict__ out) {
  __shared__ ushort w2s[8192];        // 16 W2 frags x 64 lanes x 8
  __shared__ ushort t1s[4][16 * 136]; // per-wave t1 tile, stride 136 (bank-safe)
  const int tid = threadIdx.x;
  const int w = tid >> 6, lane = tid & 63;
  const int q = lane >> 4, nn = lane & 15;

  for (int i = tid; i < 1024; i += 256) ((uint4*)w2s)[i] = ((const uint4*)W2f)[i];
  __syncthreads();

  float bm1v[8];
#pragma unroll
  for (int t = 0; t < 8; t++) bm1v[t] = bm1[t * 16 + nn];
  float bm2v[4], w3v[4];
#pragma unroll
  for (int t = 0; t < 4; t++) { bm2v[t] = bm2[t * 16 + nn]; w3v[t] = Wm3[t * 16 + nn]; }
  const float bm3v = bm3[0];

  const int base = blockIdx.x * 128 + w * 32;
  const int e0 = base + nn, e1 = base + 16 + nn;
  const int s0 = src[e0], d0 = dst[e0];
  const int s1 = src[e1], d1 = dst[e1];
  const float at0 = eattr[e0], at1 = eattr[e1];

  // A-fragments from global bf16 node features (lane's k-range = q*8..q*8+7)
  short8 hs0a = *(const short8*)(hb + s0 * 64 + q * 8);
  short8 hs0b = *(const short8*)(hb + s0 * 64 + 32 + q * 8);
  short8 hd0a = *(const short8*)(hb + d0 * 64 + q * 8);
  short8 hd0b = *(const short8*)(hb + d0 * 64 + 32 + q * 8);
  short8 hs1a = *(const short8*)(hb + s1 * 64 + q * 8);
  short8 hs1b = *(const short8*)(hb + s1 * 64 + 32 + q * 8);
  short8 hd1a = *(const short8*)(hb + d1 * 64 + q * 8);
  short8 hd1b = *(const short8*)(hb + d1 * 64 + 32 + q * 8);

  f32x4 acc0[8], acc1[8];
#pragma unroll
  for (int t = 0; t < 8; t++) {
    acc0[t] = (f32x4){0.f, 0.f, 0.f, 0.f};
    acc1[t] = (f32x4){0.f, 0.f, 0.f, 0.f};
  }

  short8 a6_0 = 0, a6_1 = 0;
  if (q == 0) { a6_0[0] = (short)f2bf(at0); a6_1[0] = (short)f2bf(at1); }

  MLP1_STEP(0, hs0a, hs1a)
  MLP1_STEP(1, hs0b, hs1b)
  MLP1_STEP(2, hd0a, hd1a)
  MLP1_STEP(3, hd0b, hd1b)
  MLP1_STEP(4, absdiff8(hs0a, hd0a), absdiff8(hs1a, hd1a))
  MLP1_STEP(5, absdiff8(hs0b, hd0b), absdiff8(hs1b, hd1b))
  MLP1_STEP(6, a6_0, a6_1)

  ushort* myt1 = t1s[w];
  auto do_group = [&](f32x4* acc, int g) {
    __syncthreads();
    // C-layout (row=q*4+reg edge, col=t*16+nn ch) -> LDS [edge][ch] bf16, +bias+lrelu
#pragma unroll
    for (int t = 0; t < 8; t++)
#pragma unroll
      for (int r = 0; r < 4; r++)
        myt1[(q * 4 + r) * 136 + t * 16 + nn] = f2bf(lrelu(acc[t][r] + bm1v[t]));
    __syncthreads();
    f32x4 acc2[4];
#pragma unroll
    for (int t = 0; t < 4; t++) acc2[t] = (f32x4){0.f, 0.f, 0.f, 0.f};
#pragma unroll
    for (int c2 = 0; c2 < 4; c2++) {
      short8 a = *(short8*)&myt1[nn * 136 + c2 * 32 + q * 8];
#pragma unroll
      for (int t = 0; t < 4; t++) {
        short8 b = *(short8*)&w2s[(c2 * 4 + t) * 512 + lane * 8];
        acc2[t] = __builtin_amdgcn_mfma_f32_16x16x32_bf16(a, b, acc2[t], 0, 0, 0);
      }
    }
#pragma unroll
    for (int r = 0; r < 4; r++) {
      float sum = 0.f;
#pragma unroll
      for (int t = 0; t < 4; t++) sum += lrelu(acc2[t][r] + bm2v[t]) * w3v[t];
      sum += __shfl_xor(sum, 1);
      sum += __shfl_xor(sum, 2);
      sum += __shfl_xor(sum, 4);
      sum += __shfl_xor(sum, 8);
      if (nn == 0) out[base + g * 16 + q * 4 + r] = sum + bm3v;
    }
  };
  do_group(acc0, 0);
  do_group(acc1, 1);
}

// ---------------- orchestration ----------------
extern "C" void kernel_launch(void* const* d_in, const int* in_sizes, int n_in,
                              void* d_out, int out_size, void* d_ws, size_t ws_size,
                              hipStream_t stream) {
  const float* x    = (const float*)d_in[0];
  const int*   ei   = (const int*)d_in[1];
  const float* eatt = (const float*)d_in[2];
  const float* W0 = (const float*)d_in[3];
  const float* as0 = (const float*)d_in[4];
  const float* ad0 = (const float*)d_in[5];
  const float* b0 = (const float*)d_in[6];
  const float* W1 = (const float*)d_in[7];
  const float* as1 = (const float*)d_in[8];
  const float* ad1 = (const float*)d_in[9];
  const float* b1 = (const float*)d_in[10];
  const float* W2 = (const float*)d_in[11];
  const float* as2 = (const float*)d_in[12];
  const float* ad2 = (const float*)d_in[13];
  const float* b2 = (const float*)d_in[14];
  const float* g0 = (const float*)d_in[15];
  const float* be0 = (const float*)d_in[16];
  const float* g1 = (const float*)d_in[17];
  const float* be1 = (const float*)d_in[18];
  const float* g2 = (const float*)d_in[19];
  const float* be2 = (const float*)d_in[20];
  const float* Wm1 = (const float*)d_in[21];
  const float* bm1 = (const float*)d_in[22];
  const float* Wm2 = (const float*)d_in[23];
  const float* bm2 = (const float*)d_in[24];
  const float* Wm3 = (const float*)d_in[25];
  const float* bm3 = (const float*)d_in[26];
  const int* src = ei;
  const int* dst = ei + Ee;
  float* out = (float*)d_out;

  float* ws = (float*)d_ws;
  float* h     = ws;                          // N*HD
  float* agg   = h + (size_t)Nn * HD;         // N*HD
  float* asrc  = agg + (size_t)Nn * HD;       // N*4
  float* adst  = asrc + (size_t)Nn * 4;       // N*4
  float* h2    = adst + (size_t)Nn * 4;       // N*64
  float* stats = h2 + (size_t)Nn * HIDd;      // 512
  int* deg      = (int*)(stats + 512);        // N
  int* rowstart = deg + Nn;                   // N+1 (pad to N+16 for alignment)
  int* cursor   = rowstart + Nn + 16;         // N
  int* elist    = cursor + Nn;                // E+N
  // bf16 buffers overlay h (h is dead after layer-2 gat_gather)
  ushort* hb  = (ushort*)h;                   // N*64
  ushort* W1f = hb + (size_t)Nn * 64;         // 28672
  ushort* W2f = W1f + 28672;                  // 8192

  // ---- CSR build (once; edge_index identical for all 3 layers) ----
  filli_kernel<<<(Nn + 255) / 256, 256, 0, stream>>>(deg, 1, Nn);  // self loops
  hist_kernel<<<(Ee + 255) / 256, 256, 0, stream>>>(dst, deg);
  scan_kernel<<<1, 1024, 0, stream>>>(deg, rowstart);
  cursor_init_kernel<<<(Nn + 255) / 256, 256, 0, stream>>>(rowstart, cursor);
  elist_fill_kernel<<<(Ee + Nn + 255) / 256, 256, 0, stream>>>(src, dst, cursor, elist);

  auto gat = [&](const float* xin, int K, const float* W, const float* a_s, const float* a_d,
                 const float* bias, bool concat) {
    gemm_kernel<<<dim3((Nn + 63) / 64, 4), 256, 0, stream>>>(xin, W, h, Nn, K);
    alpha_kernel<<<(Nn * NH + 3) / 4, 256, 0, stream>>>(h, a_s, a_d, asrc, adst);
    gat_gather_kernel<<<Nn, 256, 0, stream>>>(elist, rowstart, h, asrc, adst, bias, agg,
                                              concat ? 1 : 0);
  };

  // Layer 0
  gat(x, FIN, W0, as0, ad0, b0, true);
  fill_kernel<<<2, 256, 0, stream>>>(stats, 0.f, 512);
  bn_stats_kernel<<<(Nn + 127) / 128, 256, 0, stream>>>(agg, stats, Nn, HD);
  bn_apply_kernel<<<(Nn * HD + 255) / 256, 256, 0, stream>>>(agg, stats, g0, be0, HD, 1);
  // Layer 1
  gat(agg, HD, W1, as1, ad1, b1, true);
  fill_kernel<<<2, 256, 0, stream>>>(stats, 0.f, 512);
  bn_stats_kernel<<<(Nn + 127) / 128, 256, 0, stream>>>(agg, stats, Nn, HD);
  bn_apply_kernel<<<(Nn * HD + 255) / 256, 256, 0, stream>>>(agg, stats, g1, be1, HD, 1);
  // Layer 2 (concat=False)
  gat(agg, HD, W2, as2, ad2, b2, false);
  mean_heads_kernel<<<(Nn * HIDd + 255) / 256, 256, 0, stream>>>(agg, b2, h2);
  fill_kernel<<<1, 256, 0, stream>>>(stats, 0.f, 128);
  bn_stats_kernel<<<(Nn + 127) / 128, 256, 0, stream>>>(h2, stats, Nn, HIDd);
  bn_apply_kernel<<<(Nn * HIDd + 255) / 256, 256, 0, stream>>>(h2, stats, g2, be2, HIDd, 0);
  // ---- Edge MLP (MFMA bf16) ----  (h region is dead now; safe to overlay)
  cvt_bf16_kernel<<<(Nn * 64 + 255) / 256, 256, 0, stream>>>(h2, hb, Nn * 64);
  w1frag_kernel<<<(7 * 8 * 64 * 8 + 255) / 256, 256, 0, stream>>>(Wm1, W1f);
  w2frag_kernel<<<(4 * 4 * 64 * 8 + 255) / 256, 256, 0, stream>>>(Wm2, W2f);
  edge_mlp_mfma_kernel<<<Ee / 128, 256, 0, stream>>>(hb, src, dst, eatt, W1f, W2f, bm1, bm2,
                                                     Wm3, bm3, out);
}

// Round 4
// 1591.582 us; speedup vs baseline: 3.4093x; 1.0021x over previous
//
#include <hip/hip_runtime.h>
#include <math.h>

#define Nn 50000
#define Npad 50048
#define Ee 800000
#define FIN 128
#define HIDd 64
#define NH 4
#define HD 256
#define NEG 0.2f
#define BEPS 1e-5f

typedef __attribute__((ext_vector_type(8))) short short8;
typedef __attribute__((ext_vector_type(4))) float f32x4;
typedef unsigned int uint;
typedef unsigned short ushort;

static __device__ __forceinline__ float lrelu(float x) { return x > 0.f ? x : NEG * x; }
static __device__ __forceinline__ float bf2f(ushort x) {
  return __uint_as_float(((uint)x) << 16);
}
static __device__ __forceinline__ ushort f2bf(float f) {
  uint u = __float_as_uint(f);
  return (ushort)((u + 0x7FFF + ((u >> 16) & 1)) >> 16);
}

// ---------------- utility fills ----------------
__global__ void fill_kernel(float* __restrict__ p, float v, int n) {
  int i = blockIdx.x * 256 + threadIdx.x;
  if (i < n) p[i] = v;
}

__global__ void filli_kernel(int* __restrict__ p, int v, int n) {
  int i = blockIdx.x * 256 + threadIdx.x;
  if (i < n) p[i] = v;
}

// ---------------- CSR build (edge_index is layer-invariant: build once) ----------------
__global__ void hist_kernel(const int* __restrict__ dst, int* __restrict__ deg) {
  int i = blockIdx.x * 256 + threadIdx.x;
  if (i < Ee) atomicAdd(&deg[dst[i]], 1);
}

__global__ __launch_bounds__(1024) void scan_kernel(const int* __restrict__ deg,
                                                    int* __restrict__ rowstart) {
  __shared__ int ts[1024];
  const int tid = threadIdx.x;
  const int CH = (Nn + 1023) / 1024;
  const int base = tid * CH;
  int s = 0;
  for (int j = 0; j < CH; j++) {
    int idx = base + j;
    if (idx < Nn) s += deg[idx];
  }
  ts[tid] = s;
  __syncthreads();
  for (int off = 1; off < 1024; off <<= 1) {
    int v = (tid >= off) ? ts[tid - off] : 0;
    __syncthreads();
    ts[tid] += v;
    __syncthreads();
  }
  int run = (tid == 0) ? 0 : ts[tid - 1];
  for (int j = 0; j < CH; j++) {
    int idx = base + j;
    if (idx < Nn) {
      rowstart[idx] = run;
      run += deg[idx];
      if (idx == Nn - 1) rowstart[Nn] = run;
    }
  }
}

__global__ void cursor_init_kernel(const int* __restrict__ rowstart, int* __restrict__ cursor) {
  int i = blockIdx.x * 256 + threadIdx.x;
  if (i < Nn) cursor[i] = rowstart[i];
}

__global__ void elist_fill_kernel(const int* __restrict__ src, const int* __restrict__ dst,
                                  int* __restrict__ cursor, int* __restrict__ elist) {
  int i = blockIdx.x * 256 + threadIdx.x;
  if (i >= Ee + Nn) return;
  int s, d;
  if (i < Ee) { s = src[i]; d = dst[i]; } else { s = d = i - Ee; }
  int pos = atomicAdd(&cursor[d], 1);
  elist[pos] = s;
}

// ---------------- bf16 conversions / weight swizzles ----------------
__global__ void cvt_bf16_kernel(const float* __restrict__ in, ushort* __restrict__ out, int n) {
  int i = blockIdx.x * 256 + threadIdx.x;
  if (i < n) out[i] = f2bf(in[i]);
}

// W[K,256] -> B-frag-major: Wf[((kc*16 + t)*64 + lane)*8 + j] = W[(kc*32+(lane>>4)*8+j)*256 + t*16+(lane&15)]
__global__ void wfrag_kernel(const float* __restrict__ W, ushort* __restrict__ Wf, int K) {
  int idx = blockIdx.x * 256 + threadIdx.x;
  int total = (K >> 5) * 16 * 64 * 8;
  if (idx >= total) return;
  int j = idx & 7, lane = (idx >> 3) & 63, t = (idx >> 9) & 15, kc = idx >> 13;
  int n = t * 16 + (lane & 15);
  int k = kc * 32 + ((lane >> 4) << 3) + j;
  Wf[idx] = f2bf(W[k * 256 + n]);
}

// ---------------- MFMA GEMM: C[Npad,256] bf16 = A[Npad,K] bf16 @ Wf ----------------
__global__ __launch_bounds__(256) void gemm_mfma_kernel(const ushort* __restrict__ A,
                                                        const ushort* __restrict__ Bf,
                                                        ushort* __restrict__ C, int K) {
  const int tid = threadIdx.x;
  const int w = tid >> 6, lane = tid & 63;
  const int q = lane >> 4, nn = lane & 15;
  const int m0 = blockIdx.x * 128 + w * 32;
  const int cb = blockIdx.y;
  f32x4 acc[2][8];
#pragma unroll
  for (int tm = 0; tm < 2; tm++)
#pragma unroll
    for (int t = 0; t < 8; t++) acc[tm][t] = (f32x4){0.f, 0.f, 0.f, 0.f};
  const int nkc = K >> 5;
  for (int kc = 0; kc < nkc; kc++) {
    short8 a0 = *(const short8*)(A + (size_t)(m0 + nn) * K + kc * 32 + q * 8);
    short8 a1 = *(const short8*)(A + (size_t)(m0 + 16 + nn) * K + kc * 32 + q * 8);
#pragma unroll
    for (int t = 0; t < 8; t++) {
      short8 b = *(const short8*)(Bf + ((size_t)((kc * 16 + cb * 8 + t) * 64 + lane)) * 8);
      acc[0][t] = __builtin_amdgcn_mfma_f32_16x16x32_bf16(a0, b, acc[0][t], 0, 0, 0);
      acc[1][t] = __builtin_amdgcn_mfma_f32_16x16x32_bf16(a1, b, acc[1][t], 0, 0, 0);
    }
  }
#pragma unroll
  for (int tm = 0; tm < 2; tm++)
#pragma unroll
    for (int t = 0; t < 8; t++)
#pragma unroll
      for (int r = 0; r < 4; r++) {
        int row = m0 + tm * 16 + q * 4 + r;
        C[(size_t)row * 256 + cb * 128 + t * 16 + nn] = f2bf(acc[tm][t][r]);
      }
}

// ---------------- alpha_src / alpha_dst: wave per (node, head), bf16 h ----------------
__global__ __launch_bounds__(256) void alpha_kernel(const ushort* __restrict__ h,
                                                    const float* __restrict__ a_s,
                                                    const float* __restrict__ a_d,
                                                    float* __restrict__ asrc,
                                                    float* __restrict__ adst) {
  int wid = blockIdx.x * 4 + (threadIdx.x >> 6);
  int lane = threadIdx.x & 63;
  if (wid >= Nn * NH) return;
  int n = wid >> 2, hh = wid & 3;
  float hv = bf2f(h[(size_t)n * HD + hh * HIDd + lane]);
  float vs = hv * a_s[hh * HIDd + lane];
  float vd = hv * a_d[hh * HIDd + lane];
#pragma unroll
  for (int off = 32; off > 0; off >>= 1) {
    vs += __shfl_down(vs, off);
    vd += __shfl_down(vd, off);
  }
  if (lane == 0) { asrc[wid] = vs; adst[wid] = vd; }
}

// ---------------- fused attention gather: block per node, wave per head, bf16 h ----------------
__global__ __launch_bounds__(256) void gat_gather_kernel(
    const int* __restrict__ elist, const int* __restrict__ rowstart,
    const ushort* __restrict__ h, const float* __restrict__ asrc,
    const float* __restrict__ adst, const float* __restrict__ bias,
    float* __restrict__ agg, int concat) {
  const int n = blockIdx.x;
  const int hh = threadIdx.x >> 6;
  const int lane = threadIdx.x & 63;
  const int start = rowstart[n], end = rowstart[n + 1];
  const float adstv = adst[n * 4 + hh];
  float m = -INFINITY;
  for (int j = start + lane; j < end; j += 64)
    m = fmaxf(m, lrelu(asrc[elist[j] * 4 + hh] + adstv));
#pragma unroll
  for (int off = 32; off > 0; off >>= 1) m = fmaxf(m, __shfl_xor(m, off));
  float acc = 0.f, den = 0.f;
  for (int c = start; c < end; c += 64) {
    int cl = min(64, end - c);
    float w = 0.f;
    int sidx = 0;
    if (lane < cl) {
      sidx = elist[c + lane];
      w = expf(lrelu(asrc[sidx * 4 + hh] + adstv) - m);
    }
    den += w;
    for (int j = 0; j < cl; j++) {
      float wj = __shfl(w, j);
      int sj = __shfl(sidx, j);
      acc += wj * bf2f(h[(size_t)sj * HD + hh * HIDd + lane]);
    }
  }
#pragma unroll
  for (int off = 32; off > 0; off >>= 1) den += __shfl_xor(den, off);
  float o = acc / den;
  if (concat) o += bias[hh * HIDd + lane];
  agg[(size_t)n * HD + hh * HIDd + lane] = o;
}

// ---------------- layer-2 head mean ----------------
__global__ void mean_heads_kernel(const float* __restrict__ agg, const float* __restrict__ b,
                                  float* __restrict__ h2) {
  int i = blockIdx.x * 256 + threadIdx.x;
  if (i >= Nn * HIDd) return;
  int n = i >> 6, dd = i & 63;
  const float* r = agg + (size_t)n * HD + dd;
  h2[i] = 0.25f * (r[0] + r[64] + r[128] + r[192]) + b[dd];
}

// ---------------- BatchNorm ----------------
__global__ void bn_stats_kernel(const float* __restrict__ x, float* __restrict__ stats,
                                int nrows, int C) {
  int r0 = blockIdx.x * 512;
  int tpc = 256 / C;
  int c = threadIdx.x % C;
  int ro = threadIdx.x / C;
  int rend = min(r0 + 512, nrows);
  float s = 0.f, s2 = 0.f;
  for (int r = r0 + ro; r < rend; r += tpc) {
    float v = x[(size_t)r * C + c];
    s += v; s2 += v * v;
  }
  atomicAdd(&stats[c], s);
  atomicAdd(&stats[C + c], s2);
}

// reads fp32, applies BN(+lrelu), writes bf16
__global__ void bn_apply_bf16_kernel(const float* __restrict__ x, const float* __restrict__ stats,
                                     const float* __restrict__ g, const float* __restrict__ be,
                                     ushort* __restrict__ outb, int C, int do_lrelu) {
  int i = blockIdx.x * 256 + threadIdx.x;
  if (i >= Nn * C) return;
  int c = i % C;
  float mu = stats[c] * (1.f / Nn);
  float var = stats[C + c] * (1.f / Nn) - mu * mu;
  float y = (x[i] - mu) * rsqrtf(var + BEPS) * g[c] + be[c];
  if (do_lrelu) y = lrelu(y);
  outb[i] = f2bf(y);
}

// ---------------- edge-MLP weight swizzles ----------------
// Wm1[193,128] -> B-frag-major bf16, K padded to 224: [(chunk*8+tile)*64+lane]*8+j
__global__ void w1frag_kernel(const float* __restrict__ Wm1, ushort* __restrict__ W1f) {
  int idx = blockIdx.x * 256 + threadIdx.x;
  if (idx >= 7 * 8 * 64 * 8) return;
  int j = idx & 7, lane = (idx >> 3) & 63, tile = (idx >> 9) & 7, chunk = idx >> 12;
  int n = tile * 16 + (lane & 15);
  int k = chunk * 32 + (lane >> 4) * 8 + j;
  W1f[idx] = (k < 193) ? f2bf(Wm1[k * 128 + n]) : (ushort)0;
}

// Wm2[128,64] -> B-frag-major bf16: [(chunk*4+tile)*64+lane]*8+j
__global__ void w2frag_kernel(const float* __restrict__ Wm2, ushort* __restrict__ W2f) {
  int idx = blockIdx.x * 256 + threadIdx.x;
  if (idx >= 4 * 4 * 64 * 8) return;
  int j = idx & 7, lane = (idx >> 3) & 63, tile = (idx >> 9) & 3, chunk = idx >> 11;
  int n = tile * 16 + (lane & 15);
  int k = chunk * 32 + (lane >> 4) * 8 + j;
  W2f[idx] = f2bf(Wm2[k * 64 + n]);
}

// ---------------- Edge MLP via MFMA: [hs,hd,|hs-hd|,attr](224 pad) ->128 ->64 ->1 ----------------
static __device__ __forceinline__ short8 absdiff8(short8 a, short8 b) {
  short8 r;
#pragma unroll
  for (int j = 0; j < 8; j++) r[j] = (short)f2bf(fabsf(bf2f((ushort)a[j]) - bf2f((ushort)b[j])));
  return r;
}

#define MLP1_STEP(c, e0x, e1x)                                                         \
  {                                                                                    \
    short8 _a0 = (e0x);                                                                \
    short8 _a1 = (e1x);                                                                \
    const uint4* bp = (const uint4*)W1f + (c) * 512 + lane;                            \
    _Pragma("unroll") for (int t = 0; t < 8; t++) {                                    \
      uint4 braw = bp[t * 64];                                                         \
      short8 b = *(short8*)&braw;                                                      \
      acc0[t] = __builtin_amdgcn_mfma_f32_16x16x32_bf16(_a0, b, acc0[t], 0, 0, 0);     \
      acc1[t] = __builtin_amdgcn_mfma_f32_16x16x32_bf16(_a1, b, acc1[t], 0, 0, 0);     \
    }                                                                                  \
  }

__global__ __launch_bounds__(256) void edge_mlp_mfma_kernel(
    const ushort* __restrict__ hb, const int* __restrict__ src, const int* __restrict__ dst,
    const float* __restrict__ eattr, const ushort* __restrict__ W1f,
    const ushort* __restrict__ W2f, const float* __restrict__ bm1,
    const float* __restrict__ bm2, const float* __restrict__ Wm3,
    const float* __restrict__ bm3, float* __restrict__ out) {
  __shared__ ushort w2s[8192];        // 16 W2 frags x 64 lanes x 8
  __shared__ ushort t1s[4][16 * 136]; // per-wave t1 tile, stride 136 (bank-safe)
  const int tid = threadIdx.x;
  const int w = tid >> 6, lane = tid & 63;
  const int q = lane >> 4, nn = lane & 15;

  for (int i = tid; i < 1024; i += 256) ((uint4*)w2s)[i] = ((const uint4*)W2f)[i];
  __syncthreads();

  float bm1v[8];
#pragma unroll
  for (int t = 0; t < 8; t++) bm1v[t] = bm1[t * 16 + nn];
  float bm2v[4], w3v[4];
#pragma unroll
  for (int t = 0; t < 4; t++) { bm2v[t] = bm2[t * 16 + nn]; w3v[t] = Wm3[t * 16 + nn]; }
  const float bm3v = bm3[0];

  const int base = blockIdx.x * 128 + w * 32;
  const int e0 = base + nn, e1 = base + 16 + nn;
  const int s0 = src[e0], d0 = dst[e0];
  const int s1 = src[e1], d1 = dst[e1];
  const float at0 = eattr[e0], at1 = eattr[e1];

  short8 hs0a = *(const short8*)(hb + s0 * 64 + q * 8);
  short8 hs0b = *(const short8*)(hb + s0 * 64 + 32 + q * 8);
  short8 hd0a = *(const short8*)(hb + d0 * 64 + q * 8);
  short8 hd0b = *(const short8*)(hb + d0 * 64 + 32 + q * 8);
  short8 hs1a = *(const short8*)(hb + s1 * 64 + q * 8);
  short8 hs1b = *(const short8*)(hb + s1 * 64 + 32 + q * 8);
  short8 hd1a = *(const short8*)(hb + d1 * 64 + q * 8);
  short8 hd1b = *(const short8*)(hb + d1 * 64 + 32 + q * 8);

  f32x4 acc0[8], acc1[8];
#pragma unroll
  for (int t = 0; t < 8; t++) {
    acc0[t] = (f32x4){0.f, 0.f, 0.f, 0.f};
    acc1[t] = (f32x4){0.f, 0.f, 0.f, 0.f};
  }

  short8 a6_0 = 0, a6_1 = 0;
  if (q == 0) { a6_0[0] = (short)f2bf(at0); a6_1[0] = (short)f2bf(at1); }

  MLP1_STEP(0, hs0a, hs1a)
  MLP1_STEP(1, hs0b, hs1b)
  MLP1_STEP(2, hd0a, hd1a)
  MLP1_STEP(3, hd0b, hd1b)
  MLP1_STEP(4, absdiff8(hs0a, hd0a), absdiff8(hs1a, hd1a))
  MLP1_STEP(5, absdiff8(hs0b, hd0b), absdiff8(hs1b, hd1b))
  MLP1_STEP(6, a6_0, a6_1)

  ushort* myt1 = t1s[w];
  auto do_group = [&](f32x4* acc, int g) {
    __syncthreads();
#pragma unroll
    for (int t = 0; t < 8; t++)
#pragma unroll
      for (int r = 0; r < 4; r++)
        myt1[(q * 4 + r) * 136 + t * 16 + nn] = f2bf(lrelu(acc[t][r] + bm1v[t]));
    __syncthreads();
    f32x4 acc2[4];
#pragma unroll
    for (int t = 0; t < 4; t++) acc2[t] = (f32x4){0.f, 0.f, 0.f, 0.f};
#pragma unroll
    for (int c2 = 0; c2 < 4; c2++) {
      short8 a = *(short8*)&myt1[nn * 136 + c2 * 32 + q * 8];
#pragma unroll
      for (int t = 0; t < 4; t++) {
        short8 b = *(short8*)&w2s[(c2 * 4 + t) * 512 + lane * 8];
        acc2[t] = __builtin_amdgcn_mfma_f32_16x16x32_bf16(a, b, acc2[t], 0, 0, 0);
      }
    }
#pragma unroll
    for (int r = 0; r < 4; r++) {
      float sum = 0.f;
#pragma unroll
      for (int t = 0; t < 4; t++) sum += lrelu(acc2[t][r] + bm2v[t]) * w3v[t];
      sum += __shfl_xor(sum, 1);
      sum += __shfl_xor(sum, 2);
      sum += __shfl_xor(sum, 4);
      sum += __shfl_xor(sum, 8);
      if (nn == 0) out[base + g * 16 + q * 4 + r] = sum + bm3v;
    }
  };
  do_group(acc0, 0);
  do_group(acc1, 1);
}

// ---------------- orchestration ----------------
extern "C" void kernel_launch(void* const* d_in, const int* in_sizes, int n_in,
                              void* d_out, int out_size, void* d_ws, size_t ws_size,
                              hipStream_t stream) {
  const float* x    = (const float*)d_in[0];
  const int*   ei   = (const int*)d_in[1];
  const float* eatt = (const float*)d_in[2];
  const float* W0 = (const float*)d_in[3];
  const float* as0 = (const float*)d_in[4];
  const float* ad0 = (const float*)d_in[5];
  const float* b0 = (const float*)d_in[6];
  const float* W1 = (const float*)d_in[7];
  const float* as1 = (const float*)d_in[8];
  const float* ad1 = (const float*)d_in[9];
  const float* b1 = (const float*)d_in[10];
  const float* W2 = (const float*)d_in[11];
  const float* as2 = (const float*)d_in[12];
  const float* ad2 = (const float*)d_in[13];
  const float* b2 = (const float*)d_in[14];
  const float* g0 = (const float*)d_in[15];
  const float* be0 = (const float*)d_in[16];
  const float* g1 = (const float*)d_in[17];
  const float* be1 = (const float*)d_in[18];
  const float* g2 = (const float*)d_in[19];
  const float* be2 = (const float*)d_in[20];
  const float* Wm1 = (const float*)d_in[21];
  const float* bm1 = (const float*)d_in[22];
  const float* Wm2 = (const float*)d_in[23];
  const float* bm2 = (const float*)d_in[24];
  const float* Wm3 = (const float*)d_in[25];
  const float* bm3 = (const float*)d_in[26];
  const int* src = ei;
  const int* dst = ei + Ee;
  float* out = (float*)d_out;

  // ---- workspace layout (with aliasing; all stream-ordered) ----
  char* w = (char*)d_ws;
  float*  agg  = (float*)w;                                   // Npad*256 fp32 (gather out)
  ushort* xb   = (ushort*)w;                                  // alias: Npad*128 bf16 (layer-0 A)
  ushort* hB   = (ushort*)(w + (size_t)Npad * 256 * 4);       // Npad*256 bf16 (gemm out)
  float*  h2   = (float*)hB;                                  // alias (layer-2 only): Nn*64 fp32
  ushort* aggb = (ushort*)(w + (size_t)Npad * 256 * 6);       // Npad*256 bf16 (post-BN A)
  ushort* hb2  = aggb;                                        // alias: Nn*64 bf16 (edge-MLP feat)
  float*  asrc = (float*)(w + (size_t)Npad * 256 * 8);        // Nn*4
  float*  adst = asrc + (size_t)Nn * 4;                       // Nn*4
  float*  stats = adst + (size_t)Nn * 4;                      // 512
  int* deg      = (int*)(stats + 512);                        // Nn
  int* rowstart = deg + Nn;                                   // Nn+16
  int* cursor   = rowstart + Nn + 16;                         // Nn
  int* elist    = cursor + Nn;                                // Ee+Nn
  ushort* W0f  = (ushort*)(elist + Ee + Nn);                  // 32768
  ushort* W1gf = W0f + 32768;                                 // 65536
  ushort* W2gf = W1gf + 65536;                                // 65536
  ushort* eW1f = W2gf + 65536;                                // 28672
  ushort* eW2f = eW1f + 28672;                                // 8192

  // ---- CSR build (once; edge_index identical for all 3 layers) ----
  filli_kernel<<<(Nn + 255) / 256, 256, 0, stream>>>(deg, 1, Nn);  // self loops
  hist_kernel<<<(Ee + 255) / 256, 256, 0, stream>>>(dst, deg);
  scan_kernel<<<1, 1024, 0, stream>>>(deg, rowstart);
  cursor_init_kernel<<<(Nn + 255) / 256, 256, 0, stream>>>(rowstart, cursor);
  elist_fill_kernel<<<(Ee + Nn + 255) / 256, 256, 0, stream>>>(src, dst, cursor, elist);

  // ---- weight swizzles (once) ----
  wfrag_kernel<<<(32768 + 255) / 256, 256, 0, stream>>>(W0, W0f, FIN);
  wfrag_kernel<<<(65536 + 255) / 256, 256, 0, stream>>>(W1, W1gf, HD);
  wfrag_kernel<<<(65536 + 255) / 256, 256, 0, stream>>>(W2, W2gf, HD);
  w1frag_kernel<<<(7 * 8 * 64 * 8 + 255) / 256, 256, 0, stream>>>(Wm1, eW1f);
  w2frag_kernel<<<(4 * 4 * 64 * 8 + 255) / 256, 256, 0, stream>>>(Wm2, eW2f);

  auto gat = [&](const ushort* Ab, const ushort* Wf, int K, const float* a_s,
                 const float* a_d, const float* bias, bool concat) {
    gemm_mfma_kernel<<<dim3(Npad / 128, 2), 256, 0, stream>>>(Ab, Wf, hB, K);
    alpha_kernel<<<(Nn * NH + 3) / 4, 256, 0, stream>>>(hB, a_s, a_d, asrc, adst);
    gat_gather_kernel<<<Nn, 256, 0, stream>>>(elist, rowstart, hB, asrc, adst, bias, agg,
                                              concat ? 1 : 0);
  };

  // Layer 0
  cvt_bf16_kernel<<<(Nn * FIN + 255) / 256, 256, 0, stream>>>(x, xb, Nn * FIN);
  gat(xb, W0f, FIN, as0, ad0, b0, true);
  fill_kernel<<<2, 256, 0, stream>>>(stats, 0.f, 512);
  bn_stats_kernel<<<(Nn + 511) / 512, 256, 0, stream>>>(agg, stats, Nn, HD);
  bn_apply_bf16_kernel<<<(Nn * HD + 255) / 256, 256, 0, stream>>>(agg, stats, g0, be0, aggb, HD, 1);
  // Layer 1
  gat(aggb, W1gf, HD, as1, ad1, b1, true);
  fill_kernel<<<2, 256, 0, stream>>>(stats, 0.f, 512);
  bn_stats_kernel<<<(Nn + 511) / 512, 256, 0, stream>>>(agg, stats, Nn, HD);
  bn_apply_bf16_kernel<<<(Nn * HD + 255) / 256, 256, 0, stream>>>(agg, stats, g1, be1, aggb, HD, 1);
  // Layer 2 (concat=False)
  gat(aggb, W2gf, HD, as2, ad2, b2, false);
  mean_heads_kernel<<<(Nn * HIDd + 255) / 256, 256, 0, stream>>>(agg, b2, h2);
  fill_kernel<<<1, 256, 0, stream>>>(stats, 0.f, 128);
  bn_stats_kernel<<<(Nn + 511) / 512, 256, 0, stream>>>(h2, stats, Nn, HIDd);
  bn_apply_bf16_kernel<<<(Nn * HIDd + 255) / 256, 256, 0, stream>>>(h2, stats, g2, be2, hb2,
                                                                    HIDd, 0);
  // ---- Edge MLP (MFMA bf16) ----
  edge_mlp_mfma_kernel<<<Ee / 128, 256, 0, stream>>>(hb2, src, dst, eatt, eW1f, eW2f, bm1, bm2,
                                                     Wm3, bm3, out);
}

// Round 5
// 1350.452 us; speedup vs baseline: 4.0180x; 1.1786x over previous
//
#include <hip/hip_runtime.h>
#include <math.h>

#define Nn 50000
#define Npad 50048
#define Ee 800000
#define FIN 128
#define HIDd 64
#define NH 4
#define HD 256
#define NEG 0.2f
#define BEPS 1e-5f

typedef __attribute__((ext_vector_type(8))) short short8;
typedef __attribute__((ext_vector_type(4))) float f32x4;
typedef unsigned int uint;
typedef unsigned short ushort;

static __device__ __forceinline__ float lrelu(float x) { return x > 0.f ? x : NEG * x; }
static __device__ __forceinline__ float bf2f(ushort x) {
  return __uint_as_float(((uint)x) << 16);
}
static __device__ __forceinline__ ushort f2bf(float f) {
  uint u = __float_as_uint(f);
  return (ushort)((u + 0x7FFF + ((u >> 16) & 1)) >> 16);
}

// ---------------- utility fills ----------------
__global__ void fill_kernel(float* __restrict__ p, float v, int n) {
  int i = blockIdx.x * 256 + threadIdx.x;
  if (i < n) p[i] = v;
}

__global__ void filli_kernel(int* __restrict__ p, int v, int n) {
  int i = blockIdx.x * 256 + threadIdx.x;
  if (i < n) p[i] = v;
}

// ---------------- CSR build (edge_index is layer-invariant: build once) ----------------
__global__ void hist_kernel(const int* __restrict__ dst, int* __restrict__ deg) {
  int i = blockIdx.x * 256 + threadIdx.x;
  if (i < Ee) atomicAdd(&deg[dst[i]], 1);
}

__global__ __launch_bounds__(1024) void scan_kernel(const int* __restrict__ deg,
                                                    int* __restrict__ rowstart) {
  __shared__ int ts[1024];
  const int tid = threadIdx.x;
  const int CH = (Nn + 1023) / 1024;
  const int base = tid * CH;
  int s = 0;
  for (int j = 0; j < CH; j++) {
    int idx = base + j;
    if (idx < Nn) s += deg[idx];
  }
  ts[tid] = s;
  __syncthreads();
  for (int off = 1; off < 1024; off <<= 1) {
    int v = (tid >= off) ? ts[tid - off] : 0;
    __syncthreads();
    ts[tid] += v;
    __syncthreads();
  }
  int run = (tid == 0) ? 0 : ts[tid - 1];
  for (int j = 0; j < CH; j++) {
    int idx = base + j;
    if (idx < Nn) {
      rowstart[idx] = run;
      run += deg[idx];
      if (idx == Nn - 1) rowstart[Nn] = run;
    }
  }
}

__global__ void cursor_init_kernel(const int* __restrict__ rowstart, int* __restrict__ cursor) {
  int i = blockIdx.x * 256 + threadIdx.x;
  if (i < Nn) cursor[i] = rowstart[i];
}

__global__ void elist_fill_kernel(const int* __restrict__ src, const int* __restrict__ dst,
                                  int* __restrict__ cursor, int* __restrict__ elist) {
  int i = blockIdx.x * 256 + threadIdx.x;
  if (i >= Ee + Nn) return;
  int s, d;
  if (i < Ee) { s = src[i]; d = dst[i]; } else { s = d = i - Ee; }
  int pos = atomicAdd(&cursor[d], 1);
  elist[pos] = s;
}

// ---------------- bf16 conversions / weight swizzles ----------------
__global__ void cvt_bf16_kernel(const float* __restrict__ in, ushort* __restrict__ out, int n) {
  int i = blockIdx.x * 256 + threadIdx.x;
  if (i < n) out[i] = f2bf(in[i]);
}

// W[K,256] -> B-frag-major: Wf[((kc*16 + t)*64 + lane)*8 + j] = W[(kc*32+(lane>>4)*8+j)*256 + t*16+(lane&15)]
__global__ void wfrag_kernel(const float* __restrict__ W, ushort* __restrict__ Wf, int K) {
  int idx = blockIdx.x * 256 + threadIdx.x;
  int total = (K >> 5) * 16 * 64 * 8;
  if (idx >= total) return;
  int j = idx & 7, lane = (idx >> 3) & 63, t = (idx >> 9) & 15, kc = idx >> 13;
  int n = t * 16 + (lane & 15);
  int k = kc * 32 + ((lane >> 4) << 3) + j;
  Wf[idx] = f2bf(W[k * 256 + n]);
}

// ---------------- MFMA GEMM: C[Npad,256] bf16 = A[Npad,K] bf16 @ Wf ----------------
__global__ __launch_bounds__(256) void gemm_mfma_kernel(const ushort* __restrict__ A,
                                                        const ushort* __restrict__ Bf,
                                                        ushort* __restrict__ C, int K) {
  const int tid = threadIdx.x;
  const int w = tid >> 6, lane = tid & 63;
  const int q = lane >> 4, nn = lane & 15;
  const int m0 = blockIdx.x * 128 + w * 32;
  const int cb = blockIdx.y;
  f32x4 acc[2][8];
#pragma unroll
  for (int tm = 0; tm < 2; tm++)
#pragma unroll
    for (int t = 0; t < 8; t++) acc[tm][t] = (f32x4){0.f, 0.f, 0.f, 0.f};
  const int nkc = K >> 5;
  for (int kc = 0; kc < nkc; kc++) {
    short8 a0 = *(const short8*)(A + (size_t)(m0 + nn) * K + kc * 32 + q * 8);
    short8 a1 = *(const short8*)(A + (size_t)(m0 + 16 + nn) * K + kc * 32 + q * 8);
#pragma unroll
    for (int t = 0; t < 8; t++) {
      short8 b = *(const short8*)(Bf + ((size_t)((kc * 16 + cb * 8 + t) * 64 + lane)) * 8);
      acc[0][t] = __builtin_amdgcn_mfma_f32_16x16x32_bf16(a0, b, acc[0][t], 0, 0, 0);
      acc[1][t] = __builtin_amdgcn_mfma_f32_16x16x32_bf16(a1, b, acc[1][t], 0, 0, 0);
    }
  }
#pragma unroll
  for (int tm = 0; tm < 2; tm++)
#pragma unroll
    for (int t = 0; t < 8; t++)
#pragma unroll
      for (int r = 0; r < 4; r++) {
        int row = m0 + tm * 16 + q * 4 + r;
        C[(size_t)row * 256 + cb * 128 + t * 16 + nn] = f2bf(acc[tm][t][r]);
      }
}

// ---------------- alpha_src / alpha_dst: wave per (node, head), bf16 h ----------------
__global__ __launch_bounds__(256) void alpha_kernel(const ushort* __restrict__ h,
                                                    const float* __restrict__ a_s,
                                                    const float* __restrict__ a_d,
                                                    float* __restrict__ asrc,
                                                    float* __restrict__ adst) {
  int wid = blockIdx.x * 4 + (threadIdx.x >> 6);
  int lane = threadIdx.x & 63;
  if (wid >= Nn * NH) return;
  int n = wid >> 2, hh = wid & 3;
  float hv = bf2f(h[(size_t)n * HD + hh * HIDd + lane]);
  float vs = hv * a_s[hh * HIDd + lane];
  float vd = hv * a_d[hh * HIDd + lane];
#pragma unroll
  for (int off = 32; off > 0; off >>= 1) {
    vs += __shfl_down(vs, off);
    vd += __shfl_down(vd, off);
  }
  if (lane == 0) { asrc[wid] = vs; adst[wid] = vd; }
}

// ---------------- fused attention gather: block per node, wave per head, bf16 h ----
// 4-way unrolled inner loop: 4 independent h-row loads in flight per wave (MLP fix)
__global__ __launch_bounds__(256) void gat_gather_kernel(
    const int* __restrict__ elist, const int* __restrict__ rowstart,
    const ushort* __restrict__ h, const float* __restrict__ asrc,
    const float* __restrict__ adst, const float* __restrict__ bias,
    float* __restrict__ agg, int concat) {
  const int n = blockIdx.x;
  const int hh = threadIdx.x >> 6;
  const int lane = threadIdx.x & 63;
  const int start = rowstart[n], end = rowstart[n + 1];
  const float adstv = adst[n * 4 + hh];
  const ushort* hcol = h + hh * HIDd + lane;
  float m = -INFINITY;
  for (int j = start + lane; j < end; j += 64)
    m = fmaxf(m, lrelu(asrc[elist[j] * 4 + hh] + adstv));
#pragma unroll
  for (int off = 32; off > 0; off >>= 1) m = fmaxf(m, __shfl_xor(m, off));
  float acc = 0.f, den = 0.f;
  for (int c = start; c < end; c += 64) {
    int cl = min(64, end - c);
    float w = 0.f;
    int sidx = 0;
    if (lane < cl) {
      sidx = elist[c + lane];
      w = expf(lrelu(asrc[sidx * 4 + hh] + adstv) - m);
    }
    den += w;
    int j = 0;
    for (; j + 4 <= cl; j += 4) {
      int s0 = __shfl(sidx, j), s1 = __shfl(sidx, j + 1);
      int s2 = __shfl(sidx, j + 2), s3 = __shfl(sidx, j + 3);
      float w0 = __shfl(w, j), w1 = __shfl(w, j + 1);
      float w2 = __shfl(w, j + 2), w3 = __shfl(w, j + 3);
      float v0 = bf2f(hcol[(size_t)s0 * HD]);
      float v1 = bf2f(hcol[(size_t)s1 * HD]);
      float v2 = bf2f(hcol[(size_t)s2 * HD]);
      float v3 = bf2f(hcol[(size_t)s3 * HD]);
      acc = fmaf(w0, v0, acc);
      acc = fmaf(w1, v1, acc);
      acc = fmaf(w2, v2, acc);
      acc = fmaf(w3, v3, acc);
    }
    for (; j < cl; j++) {
      int sj = __shfl(sidx, j);
      float wj = __shfl(w, j);
      acc = fmaf(wj, bf2f(hcol[(size_t)sj * HD]), acc);
    }
  }
#pragma unroll
  for (int off = 32; off > 0; off >>= 1) den += __shfl_xor(den, off);
  float o = acc / den;
  if (concat) o += bias[hh * HIDd + lane];
  agg[(size_t)n * HD + hh * HIDd + lane] = o;
}

// ---------------- layer-2 head mean ----------------
__global__ void mean_heads_kernel(const float* __restrict__ agg, const float* __restrict__ b,
                                  float* __restrict__ h2) {
  int i = blockIdx.x * 256 + threadIdx.x;
  if (i >= Nn * HIDd) return;
  int n = i >> 6, dd = i & 63;
  const float* r = agg + (size_t)n * HD + dd;
  h2[i] = 0.25f * (r[0] + r[64] + r[128] + r[192]) + b[dd];
}

// ---------------- BatchNorm ----------------
__global__ void bn_stats_kernel(const float* __restrict__ x, float* __restrict__ stats,
                                int nrows, int C) {
  int r0 = blockIdx.x * 512;
  int tpc = 256 / C;
  int c = threadIdx.x % C;
  int ro = threadIdx.x / C;
  int rend = min(r0 + 512, nrows);
  float s = 0.f, s2 = 0.f;
  for (int r = r0 + ro; r < rend; r += tpc) {
    float v = x[(size_t)r * C + c];
    s += v; s2 += v * v;
  }
  atomicAdd(&stats[c], s);
  atomicAdd(&stats[C + c], s2);
}

// reads fp32, applies BN(+lrelu), writes bf16
__global__ void bn_apply_bf16_kernel(const float* __restrict__ x, const float* __restrict__ stats,
                                     const float* __restrict__ g, const float* __restrict__ be,
                                     ushort* __restrict__ outb, int C, int do_lrelu) {
  int i = blockIdx.x * 256 + threadIdx.x;
  if (i >= Nn * C) return;
  int c = i % C;
  float mu = stats[c] * (1.f / Nn);
  float var = stats[C + c] * (1.f / Nn) - mu * mu;
  float y = (x[i] - mu) * rsqrtf(var + BEPS) * g[c] + be[c];
  if (do_lrelu) y = lrelu(y);
  outb[i] = f2bf(y);
}

// ---------------- edge-MLP weight swizzles ----------------
__global__ void w1frag_kernel(const float* __restrict__ Wm1, ushort* __restrict__ W1f) {
  int idx = blockIdx.x * 256 + threadIdx.x;
  if (idx >= 7 * 8 * 64 * 8) return;
  int j = idx & 7, lane = (idx >> 3) & 63, tile = (idx >> 9) & 7, chunk = idx >> 12;
  int n = tile * 16 + (lane & 15);
  int k = chunk * 32 + (lane >> 4) * 8 + j;
  W1f[idx] = (k < 193) ? f2bf(Wm1[k * 128 + n]) : (ushort)0;
}

__global__ void w2frag_kernel(const float* __restrict__ Wm2, ushort* __restrict__ W2f) {
  int idx = blockIdx.x * 256 + threadIdx.x;
  if (idx >= 4 * 4 * 64 * 8) return;
  int j = idx & 7, lane = (idx >> 3) & 63, tile = (idx >> 9) & 3, chunk = idx >> 11;
  int n = tile * 16 + (lane & 15);
  int k = chunk * 32 + (lane >> 4) * 8 + j;
  W2f[idx] = f2bf(Wm2[k * 64 + n]);
}

// ---------------- Edge MLP via MFMA: [hs,hd,|hs-hd|,attr](224 pad) ->128 ->64 ->1 ----------------
static __device__ __forceinline__ short8 absdiff8(short8 a, short8 b) {
  short8 r;
#pragma unroll
  for (int j = 0; j < 8; j++) r[j] = (short)f2bf(fabsf(bf2f((ushort)a[j]) - bf2f((ushort)b[j])));
  return r;
}

#define MLP1_STEP(c, e0x, e1x)                                                         \
  {                                                                                    \
    short8 _a0 = (e0x);                                                                \
    short8 _a1 = (e1x);                                                                \
    const uint4* bp = (const uint4*)W1f + (c) * 512 + lane;                            \
    _Pragma("unroll") for (int t = 0; t < 8; t++) {                                    \
      uint4 braw = bp[t * 64];                                                         \
      short8 b = *(short8*)&braw;                                                      \
      acc0[t] = __builtin_amdgcn_mfma_f32_16x16x32_bf16(_a0, b, acc0[t], 0, 0, 0);     \
      acc1[t] = __builtin_amdgcn_mfma_f32_16x16x32_bf16(_a1, b, acc1[t], 0, 0, 0);     \
    }                                                                                  \
  }

__global__ __launch_bounds__(256) void edge_mlp_mfma_kernel(
    const ushort* __restrict__ hb, const int* __restrict__ src, const int* __restrict__ dst,
    const float* __restrict__ eattr, const ushort* __restrict__ W1f,
    const ushort* __restrict__ W2f, const float* __restrict__ bm1,
    const float* __restrict__ bm2, const float* __restrict__ Wm3,
    const float* __restrict__ bm3, float* __restrict__ out) {
  __shared__ ushort w2s[8192];
  __shared__ ushort t1s[4][16 * 136];
  const int tid = threadIdx.x;
  const int w = tid >> 6, lane = tid & 63;
  const int q = lane >> 4, nn = lane & 15;

  for (int i = tid; i < 1024; i += 256) ((uint4*)w2s)[i] = ((const uint4*)W2f)[i];
  __syncthreads();

  float bm1v[8];
#pragma unroll
  for (int t = 0; t < 8; t++) bm1v[t] = bm1[t * 16 + nn];
  float bm2v[4], w3v[4];
#pragma unroll
  for (int t = 0; t < 4; t++) { bm2v[t] = bm2[t * 16 + nn]; w3v[t] = Wm3[t * 16 + nn]; }
  const float bm3v = bm3[0];

  const int base = blockIdx.x * 128 + w * 32;
  const int e0 = base + nn, e1 = base + 16 + nn;
  const int s0 = src[e0], d0 = dst[e0];
  const int s1 = src[e1], d1 = dst[e1];
  const float at0 = eattr[e0], at1 = eattr[e1];

  short8 hs0a = *(const short8*)(hb + s0 * 64 + q * 8);
  short8 hs0b = *(const short8*)(hb + s0 * 64 + 32 + q * 8);
  short8 hd0a = *(const short8*)(hb + d0 * 64 + q * 8);
  short8 hd0b = *(const short8*)(hb + d0 * 64 + 32 + q * 8);
  short8 hs1a = *(const short8*)(hb + s1 * 64 + q * 8);
  short8 hs1b = *(const short8*)(hb + s1 * 64 + 32 + q * 8);
  short8 hd1a = *(const short8*)(hb + d1 * 64 + q * 8);
  short8 hd1b = *(const short8*)(hb + d1 * 64 + 32 + q * 8);

  f32x4 acc0[8], acc1[8];
#pragma unroll
  for (int t = 0; t < 8; t++) {
    acc0[t] = (f32x4){0.f, 0.f, 0.f, 0.f};
    acc1[t] = (f32x4){0.f, 0.f, 0.f, 0.f};
  }

  short8 a6_0 = 0, a6_1 = 0;
  if (q == 0) { a6_0[0] = (short)f2bf(at0); a6_1[0] = (short)f2bf(at1); }

  MLP1_STEP(0, hs0a, hs1a)
  MLP1_STEP(1, hs0b, hs1b)
  MLP1_STEP(2, hd0a, hd1a)
  MLP1_STEP(3, hd0b, hd1b)
  MLP1_STEP(4, absdiff8(hs0a, hd0a), absdiff8(hs1a, hd1a))
  MLP1_STEP(5, absdiff8(hs0b, hd0b), absdiff8(hs1b, hd1b))
  MLP1_STEP(6, a6_0, a6_1)

  ushort* myt1 = t1s[w];
  auto do_group = [&](f32x4* acc, int g) {
    __syncthreads();
#pragma unroll
    for (int t = 0; t < 8; t++)
#pragma unroll
      for (int r = 0; r < 4; r++)
        myt1[(q * 4 + r) * 136 + t * 16 + nn] = f2bf(lrelu(acc[t][r] + bm1v[t]));
    __syncthreads();
    f32x4 acc2[4];
#pragma unroll
    for (int t = 0; t < 4; t++) acc2[t] = (f32x4){0.f, 0.f, 0.f, 0.f};
#pragma unroll
    for (int c2 = 0; c2 < 4; c2++) {
      short8 a = *(short8*)&myt1[nn * 136 + c2 * 32 + q * 8];
#pragma unroll
      for (int t = 0; t < 4; t++) {
        short8 b = *(short8*)&w2s[(c2 * 4 + t) * 512 + lane * 8];
        acc2[t] = __builtin_amdgcn_mfma_f32_16x16x32_bf16(a, b, acc2[t], 0, 0, 0);
      }
    }
#pragma unroll
    for (int r = 0; r < 4; r++) {
      float sum = 0.f;
#pragma unroll
      for (int t = 0; t < 4; t++) sum += lrelu(acc2[t][r] + bm2v[t]) * w3v[t];
      sum += __shfl_xor(sum, 1);
      sum += __shfl_xor(sum, 2);
      sum += __shfl_xor(sum, 4);
      sum += __shfl_xor(sum, 8);
      if (nn == 0) out[base + g * 16 + q * 4 + r] = sum + bm3v;
    }
  };
  do_group(acc0, 0);
  do_group(acc1, 1);
}

// ---------------- orchestration ----------------
extern "C" void kernel_launch(void* const* d_in, const int* in_sizes, int n_in,
                              void* d_out, int out_size, void* d_ws, size_t ws_size,
                              hipStream_t stream) {
  const float* x    = (const float*)d_in[0];
  const int*   ei   = (const int*)d_in[1];
  const float* eatt = (const float*)d_in[2];
  const float* W0 = (const float*)d_in[3];
  const float* as0 = (const float*)d_in[4];
  const float* ad0 = (const float*)d_in[5];
  const float* b0 = (const float*)d_in[6];
  const float* W1 = (const float*)d_in[7];
  const float* as1 = (const float*)d_in[8];
  const float* ad1 = (const float*)d_in[9];
  const float* b1 = (const float*)d_in[10];
  const float* W2 = (const float*)d_in[11];
  const float* as2 = (const float*)d_in[12];
  const float* ad2 = (const float*)d_in[13];
  const float* b2 = (const float*)d_in[14];
  const float* g0 = (const float*)d_in[15];
  const float* be0 = (const float*)d_in[16];
  const float* g1 = (const float*)d_in[17];
  const float* be1 = (const float*)d_in[18];
  const float* g2 = (const float*)d_in[19];
  const float* be2 = (const float*)d_in[20];
  const float* Wm1 = (const float*)d_in[21];
  const float* bm1 = (const float*)d_in[22];
  const float* Wm2 = (const float*)d_in[23];
  const float* bm2 = (const float*)d_in[24];
  const float* Wm3 = (const float*)d_in[25];
  const float* bm3 = (const float*)d_in[26];
  const int* src = ei;
  const int* dst = ei + Ee;
  float* out = (float*)d_out;

  // ---- workspace layout (with aliasing; all stream-ordered) ----
  char* w = (char*)d_ws;
  float*  agg  = (float*)w;                                   // Npad*256 fp32 (gather out)
  ushort* xb   = (ushort*)w;                                  // alias: Npad*128 bf16 (layer-0 A)
  ushort* hB   = (ushort*)(w + (size_t)Npad * 256 * 4);       // Npad*256 bf16 (gemm out)
  float*  h2   = (float*)hB;                                  // alias (layer-2 only): Nn*64 fp32
  ushort* aggb = (ushort*)(w + (size_t)Npad * 256 * 6);       // Npad*256 bf16 (post-BN A)
  ushort* hb2  = aggb;                                        // alias: Nn*64 bf16 (edge-MLP feat)
  float*  asrc = (float*)(w + (size_t)Npad * 256 * 8);        // Nn*4
  float*  adst = asrc + (size_t)Nn * 4;                       // Nn*4
  float*  stats = adst + (size_t)Nn * 4;                      // 512
  int* deg      = (int*)(stats + 512);                        // Nn
  int* rowstart = deg + Nn;                                   // Nn+16
  int* cursor   = rowstart + Nn + 16;                         // Nn
  int* elist    = cursor + Nn;                                // Ee+Nn
  ushort* W0f  = (ushort*)(elist + Ee + Nn);                  // 32768
  ushort* W1gf = W0f + 32768;                                 // 65536
  ushort* W2gf = W1gf + 65536;                                // 65536
  ushort* eW1f = W2gf + 65536;                                // 28672
  ushort* eW2f = eW1f + 28672;                                // 8192

  // ---- CSR build (once; edge_index identical for all 3 layers) ----
  filli_kernel<<<(Nn + 255) / 256, 256, 0, stream>>>(deg, 1, Nn);  // self loops
  hist_kernel<<<(Ee + 255) / 256, 256, 0, stream>>>(dst, deg);
  scan_kernel<<<1, 1024, 0, stream>>>(deg, rowstart);
  cursor_init_kernel<<<(Nn + 255) / 256, 256, 0, stream>>>(rowstart, cursor);
  elist_fill_kernel<<<(Ee + Nn + 255) / 256, 256, 0, stream>>>(src, dst, cursor, elist);

  // ---- weight swizzles (once) ----
  wfrag_kernel<<<(32768 + 255) / 256, 256, 0, stream>>>(W0, W0f, FIN);
  wfrag_kernel<<<(65536 + 255) / 256, 256, 0, stream>>>(W1, W1gf, HD);
  wfrag_kernel<<<(65536 + 255) / 256, 256, 0, stream>>>(W2, W2gf, HD);
  w1frag_kernel<<<(7 * 8 * 64 * 8 + 255) / 256, 256, 0, stream>>>(Wm1, eW1f);
  w2frag_kernel<<<(4 * 4 * 64 * 8 + 255) / 256, 256, 0, stream>>>(Wm2, eW2f);

  auto gat = [&](const ushort* Ab, const ushort* Wf, int K, const float* a_s,
                 const float* a_d, const float* bias, bool concat) {
    gemm_mfma_kernel<<<dim3(Npad / 128, 2), 256, 0, stream>>>(Ab, Wf, hB, K);
    alpha_kernel<<<(Nn * NH + 3) / 4, 256, 0, stream>>>(hB, a_s, a_d, asrc, adst);
    gat_gather_kernel<<<Nn, 256, 0, stream>>>(elist, rowstart, hB, asrc, adst, bias, agg,
                                              concat ? 1 : 0);
  };

  // Layer 0
  cvt_bf16_kernel<<<(Nn * FIN + 255) / 256, 256, 0, stream>>>(x, xb, Nn * FIN);
  gat(xb, W0f, FIN, as0, ad0, b0, true);
  fill_kernel<<<2, 256, 0, stream>>>(stats, 0.f, 512);
  bn_stats_kernel<<<(Nn + 511) / 512, 256, 0, stream>>>(agg, stats, Nn, HD);
  bn_apply_bf16_kernel<<<(Nn * HD + 255) / 256, 256, 0, stream>>>(agg, stats, g0, be0, aggb, HD, 1);
  // Layer 1
  gat(aggb, W1gf, HD, as1, ad1, b1, true);
  fill_kernel<<<2, 256, 0, stream>>>(stats, 0.f, 512);
  bn_stats_kernel<<<(Nn + 511) / 512, 256, 0, stream>>>(agg, stats, Nn, HD);
  bn_apply_bf16_kernel<<<(Nn * HD + 255) / 256, 256, 0, stream>>>(agg, stats, g1, be1, aggb, HD, 1);
  // Layer 2 (concat=False)
  gat(aggb, W2gf, HD, as2, ad2, b2, false);
  mean_heads_kernel<<<(Nn * HIDd + 255) / 256, 256, 0, stream>>>(agg, b2, h2);
  fill_kernel<<<1, 256, 0, stream>>>(stats, 0.f, 128);
  bn_stats_kernel<<<(Nn + 511) / 512, 256, 0, stream>>>(h2, stats, Nn, HIDd);
  bn_apply_bf16_kernel<<<(Nn * HIDd + 255) / 256, 256, 0, stream>>>(h2, stats, g2, be2, hb2,
                                                                    HIDd, 0);
  // ---- Edge MLP (MFMA bf16) ----
  edge_mlp_mfma_kernel<<<Ee / 128, 256, 0, stream>>>(hb2, src, dst, eatt, eW1f, eW2f, bm1, bm2,
                                                     Wm3, bm3, out);
}

// Round 6
// 1151.639 us; speedup vs baseline: 4.7117x; 1.1726x over previous
//
#include <hip/hip_runtime.h>
#include <math.h>

#define Nn 50000
#define Npad 50048
#define Ee 800000
#define FIN 128
#define HIDd 64
#define NH 4
#define HD 256
#define NEG 0.2f
#define BEPS 1e-5f

typedef __attribute__((ext_vector_type(8))) short short8;
typedef __attribute__((ext_vector_type(4))) float f32x4;
typedef unsigned int uint;
typedef unsigned short ushort;

static __device__ __forceinline__ float lrelu(float x) { return x > 0.f ? x : NEG * x; }
static __device__ __forceinline__ float bf2f(ushort x) {
  return __uint_as_float(((uint)x) << 16);
}
static __device__ __forceinline__ ushort f2bf(float f) {
  uint u = __float_as_uint(f);
  return (ushort)((u + 0x7FFF + ((u >> 16) & 1)) >> 16);
}

// ---------------- utility fills ----------------
__global__ void fill_kernel(float* __restrict__ p, float v, int n) {
  int i = blockIdx.x * 256 + threadIdx.x;
  if (i < n) p[i] = v;
}

__global__ void filli_kernel(int* __restrict__ p, int v, int n) {
  int i = blockIdx.x * 256 + threadIdx.x;
  if (i < n) p[i] = v;
}

// ---------------- CSR build (edge_index is layer-invariant: build once) ----------------
__global__ void hist_kernel(const int* __restrict__ dst, int* __restrict__ deg) {
  int i = blockIdx.x * 256 + threadIdx.x;
  if (i < Ee) atomicAdd(&deg[dst[i]], 1);
}

__global__ __launch_bounds__(1024) void scan_kernel(const int* __restrict__ deg,
                                                    int* __restrict__ rowstart) {
  __shared__ int ts[1024];
  const int tid = threadIdx.x;
  const int CH = (Nn + 1023) / 1024;
  const int base = tid * CH;
  int s = 0;
  for (int j = 0; j < CH; j++) {
    int idx = base + j;
    if (idx < Nn) s += deg[idx];
  }
  ts[tid] = s;
  __syncthreads();
  for (int off = 1; off < 1024; off <<= 1) {
    int v = (tid >= off) ? ts[tid - off] : 0;
    __syncthreads();
    ts[tid] += v;
    __syncthreads();
  }
  int run = (tid == 0) ? 0 : ts[tid - 1];
  for (int j = 0; j < CH; j++) {
    int idx = base + j;
    if (idx < Nn) {
      rowstart[idx] = run;
      run += deg[idx];
      if (idx == Nn - 1) rowstart[Nn] = run;
    }
  }
}

__global__ void cursor_init_kernel(const int* __restrict__ rowstart, int* __restrict__ cursor) {
  int i = blockIdx.x * 256 + threadIdx.x;
  if (i < Nn) cursor[i] = rowstart[i];
}

__global__ void elist_fill_kernel(const int* __restrict__ src, const int* __restrict__ dst,
                                  int* __restrict__ cursor, int* __restrict__ elist) {
  int i = blockIdx.x * 256 + threadIdx.x;
  if (i >= Ee + Nn) return;
  int s, d;
  if (i < Ee) { s = src[i]; d = dst[i]; } else { s = d = i - Ee; }
  int pos = atomicAdd(&cursor[d], 1);
  elist[pos] = s;
}

// ---------------- bf16 conversions / weight swizzles ----------------
__global__ void cvt_bf16_kernel(const float* __restrict__ in, ushort* __restrict__ out, int n) {
  int i = blockIdx.x * 256 + threadIdx.x;
  if (i < n) out[i] = f2bf(in[i]);
}

// W[K,256] -> B-frag-major: Wf[((kc*16 + t)*64 + lane)*8 + j] = W[(kc*32+(lane>>4)*8+j)*256 + t*16+(lane&15)]
__global__ void wfrag_kernel(const float* __restrict__ W, ushort* __restrict__ Wf, int K) {
  int idx = blockIdx.x * 256 + threadIdx.x;
  int total = (K >> 5) * 16 * 64 * 8;
  if (idx >= total) return;
  int j = idx & 7, lane = (idx >> 3) & 63, t = (idx >> 9) & 15, kc = idx >> 13;
  int n = t * 16 + (lane & 15);
  int k = kc * 32 + ((lane >> 4) << 3) + j;
  Wf[idx] = f2bf(W[k * 256 + n]);
}

// ---------------- MFMA GEMM + fused alpha epilogue ----------------
// C[Npad,256] bf16 = A[Npad,K] bf16 @ Wf ; also asrc/adst[row][head] for this cb's 2 heads
__global__ __launch_bounds__(256) void gemm_mfma_kernel(
    const ushort* __restrict__ A, const ushort* __restrict__ Bf, ushort* __restrict__ C, int K,
    const float* __restrict__ a_s, const float* __restrict__ a_d,
    float* __restrict__ asrc, float* __restrict__ adst) {
  const int tid = threadIdx.x;
  const int w = tid >> 6, lane = tid & 63;
  const int q = lane >> 4, nn = lane & 15;
  const int m0 = blockIdx.x * 128 + w * 32;
  const int cb = blockIdx.y;
  f32x4 acc[2][8];
#pragma unroll
  for (int tm = 0; tm < 2; tm++)
#pragma unroll
    for (int t = 0; t < 8; t++) acc[tm][t] = (f32x4){0.f, 0.f, 0.f, 0.f};
  const int nkc = K >> 5;
  for (int kc = 0; kc < nkc; kc++) {
    short8 a0 = *(const short8*)(A + (size_t)(m0 + nn) * K + kc * 32 + q * 8);
    short8 a1 = *(const short8*)(A + (size_t)(m0 + 16 + nn) * K + kc * 32 + q * 8);
#pragma unroll
    for (int t = 0; t < 8; t++) {
      short8 b = *(const short8*)(Bf + ((size_t)((kc * 16 + cb * 8 + t) * 64 + lane)) * 8);
      acc[0][t] = __builtin_amdgcn_mfma_f32_16x16x32_bf16(a0, b, acc[0][t], 0, 0, 0);
      acc[1][t] = __builtin_amdgcn_mfma_f32_16x16x32_bf16(a1, b, acc[1][t], 0, 0, 0);
    }
  }
  // epilogue: C write + alpha partial dot (head = 2cb + (t>>2), in-head dim = (t&3)*16+nn)
  float asv[8], adv[8];
#pragma unroll
  for (int t = 0; t < 8; t++) {
    int head = 2 * cb + (t >> 2);
    int dim = (t & 3) * 16 + nn;
    asv[t] = a_s[head * 64 + dim];
    adv[t] = a_d[head * 64 + dim];
  }
#pragma unroll
  for (int tm = 0; tm < 2; tm++) {
    float ps[2][4] = {{0.f, 0.f, 0.f, 0.f}, {0.f, 0.f, 0.f, 0.f}};
    float pd[2][4] = {{0.f, 0.f, 0.f, 0.f}, {0.f, 0.f, 0.f, 0.f}};
#pragma unroll
    for (int t = 0; t < 8; t++) {
      int hp = t >> 2;
#pragma unroll
      for (int r = 0; r < 4; r++) {
        float v = acc[tm][t][r];
        int row = m0 + tm * 16 + q * 4 + r;
        C[(size_t)row * 256 + cb * 128 + t * 16 + nn] = f2bf(v);
        ps[hp][r] = fmaf(v, asv[t], ps[hp][r]);
        pd[hp][r] = fmaf(v, adv[t], pd[hp][r]);
      }
    }
#pragma unroll
    for (int hp = 0; hp < 2; hp++)
#pragma unroll
      for (int r = 0; r < 4; r++) {
        float s = ps[hp][r], d2 = pd[hp][r];
        s += __shfl_xor(s, 1); s += __shfl_xor(s, 2);
        s += __shfl_xor(s, 4); s += __shfl_xor(s, 8);
        d2 += __shfl_xor(d2, 1); d2 += __shfl_xor(d2, 2);
        d2 += __shfl_xor(d2, 4); d2 += __shfl_xor(d2, 8);
        if (nn == 0) {
          int row = m0 + tm * 16 + q * 4 + r;
          asrc[row * 4 + 2 * cb + hp] = s;
          adst[row * 4 + 2 * cb + hp] = d2;
        }
      }
  }
}

// ---------------- fused attention gather v3: block per node, 4 waves split edges ----
// all 4 heads per wave (one 512B row read/edge); softmax w/o max pass (logits O(1))
__global__ __launch_bounds__(256) void gat_gather_kernel(
    const int* __restrict__ elist, const int* __restrict__ rowstart,
    const ushort* __restrict__ h, const float* __restrict__ asrc,
    const float* __restrict__ adst, const float* __restrict__ bias,
    float* __restrict__ agg, int concat) {
  __shared__ float accs[4][256];
  __shared__ float dens[4][4];
  const int n = blockIdx.x;
  const int tid = threadIdx.x;
  const int w = tid >> 6, lane = tid & 63;
  const int hh = lane >> 4;
  const int start = rowstart[n], end = rowstart[n + 1];
  const float adstv = adst[n * 4 + hh];
  float4 acc = make_float4(0.f, 0.f, 0.f, 0.f);
  float den = 0.f;
  int j = start + w;
  for (; j + 12 < end; j += 16) {
    int s0 = elist[j], s1 = elist[j + 4], s2 = elist[j + 8], s3 = elist[j + 12];
    float e0 = asrc[s0 * 4 + hh] + adstv;
    float e1 = asrc[s1 * 4 + hh] + adstv;
    float e2 = asrc[s2 * 4 + hh] + adstv;
    float e3 = asrc[s3 * 4 + hh] + adstv;
    ushort4 v0 = *(const ushort4*)(h + (size_t)s0 * HD + lane * 4);
    ushort4 v1 = *(const ushort4*)(h + (size_t)s1 * HD + lane * 4);
    ushort4 v2 = *(const ushort4*)(h + (size_t)s2 * HD + lane * 4);
    ushort4 v3 = *(const ushort4*)(h + (size_t)s3 * HD + lane * 4);
    float w0 = __expf(lrelu(e0)), w1 = __expf(lrelu(e1));
    float w2 = __expf(lrelu(e2)), w3 = __expf(lrelu(e3));
    den += (w0 + w1) + (w2 + w3);
    acc.x = fmaf(w0, bf2f(v0.x), acc.x); acc.y = fmaf(w0, bf2f(v0.y), acc.y);
    acc.z = fmaf(w0, bf2f(v0.z), acc.z); acc.w = fmaf(w0, bf2f(v0.w), acc.w);
    acc.x = fmaf(w1, bf2f(v1.x), acc.x); acc.y = fmaf(w1, bf2f(v1.y), acc.y);
    acc.z = fmaf(w1, bf2f(v1.z), acc.z); acc.w = fmaf(w1, bf2f(v1.w), acc.w);
    acc.x = fmaf(w2, bf2f(v2.x), acc.x); acc.y = fmaf(w2, bf2f(v2.y), acc.y);
    acc.z = fmaf(w2, bf2f(v2.z), acc.z); acc.w = fmaf(w2, bf2f(v2.w), acc.w);
    acc.x = fmaf(w3, bf2f(v3.x), acc.x); acc.y = fmaf(w3, bf2f(v3.y), acc.y);
    acc.z = fmaf(w3, bf2f(v3.z), acc.z); acc.w = fmaf(w3, bf2f(v3.w), acc.w);
  }
  for (; j < end; j += 4) {
    int s0 = elist[j];
    float e0 = asrc[s0 * 4 + hh] + adstv;
    ushort4 v0 = *(const ushort4*)(h + (size_t)s0 * HD + lane * 4);
    float w0 = __expf(lrelu(e0));
    den += w0;
    acc.x = fmaf(w0, bf2f(v0.x), acc.x); acc.y = fmaf(w0, bf2f(v0.y), acc.y);
    acc.z = fmaf(w0, bf2f(v0.z), acc.z); acc.w = fmaf(w0, bf2f(v0.w), acc.w);
  }
  *(float4*)&accs[w][lane * 4] = acc;
  if ((lane & 15) == 0) dens[w][hh] = den;
  __syncthreads();
  const int d = tid;
  float s = (accs[0][d] + accs[1][d]) + (accs[2][d] + accs[3][d]);
  const int hd = d >> 6;
  float dn = (dens[0][hd] + dens[1][hd]) + (dens[2][hd] + dens[3][hd]);
  float o = s / dn;
  if (concat) o += bias[d];
  agg[(size_t)n * HD + d] = o;
}

// ---------------- layer-2 head mean ----------------
__global__ void mean_heads_kernel(const float* __restrict__ agg, const float* __restrict__ b,
                                  float* __restrict__ h2) {
  int i = blockIdx.x * 256 + threadIdx.x;
  if (i >= Nn * HIDd) return;
  int n = i >> 6, dd = i & 63;
  const float* r = agg + (size_t)n * HD + dd;
  h2[i] = 0.25f * (r[0] + r[64] + r[128] + r[192]) + b[dd];
}

// ---------------- BatchNorm ----------------
__global__ void bn_stats_kernel(const float* __restrict__ x, float* __restrict__ stats,
                                int nrows, int C) {
  int r0 = blockIdx.x * 512;
  int tpc = 256 / C;
  int c = threadIdx.x % C;
  int ro = threadIdx.x / C;
  int rend = min(r0 + 512, nrows);
  float s = 0.f, s2 = 0.f;
  for (int r = r0 + ro; r < rend; r += tpc) {
    float v = x[(size_t)r * C + c];
    s += v; s2 += v * v;
  }
  atomicAdd(&stats[c], s);
  atomicAdd(&stats[C + c], s2);
}

// reads fp32, applies BN(+lrelu), writes bf16
__global__ void bn_apply_bf16_kernel(const float* __restrict__ x, const float* __restrict__ stats,
                                     const float* __restrict__ g, const float* __restrict__ be,
                                     ushort* __restrict__ outb, int C, int do_lrelu) {
  int i = blockIdx.x * 256 + threadIdx.x;
  if (i >= Nn * C) return;
  int c = i % C;
  float mu = stats[c] * (1.f / Nn);
  float var = stats[C + c] * (1.f / Nn) - mu * mu;
  float y = (x[i] - mu) * rsqrtf(var + BEPS) * g[c] + be[c];
  if (do_lrelu) y = lrelu(y);
  outb[i] = f2bf(y);
}

// ---------------- edge-MLP weight swizzles ----------------
__global__ void w1frag_kernel(const float* __restrict__ Wm1, ushort* __restrict__ W1f) {
  int idx = blockIdx.x * 256 + threadIdx.x;
  if (idx >= 7 * 8 * 64 * 8) return;
  int j = idx & 7, lane = (idx >> 3) & 63, tile = (idx >> 9) & 7, chunk = idx >> 12;
  int n = tile * 16 + (lane & 15);
  int k = chunk * 32 + (lane >> 4) * 8 + j;
  W1f[idx] = (k < 193) ? f2bf(Wm1[k * 128 + n]) : (ushort)0;
}

__global__ void w2frag_kernel(const float* __restrict__ Wm2, ushort* __restrict__ W2f) {
  int idx = blockIdx.x * 256 + threadIdx.x;
  if (idx >= 4 * 4 * 64 * 8) return;
  int j = idx & 7, lane = (idx >> 3) & 63, tile = (idx >> 9) & 3, chunk = idx >> 11;
  int n = tile * 16 + (lane & 15);
  int k = chunk * 32 + (lane >> 4) * 8 + j;
  W2f[idx] = f2bf(Wm2[k * 64 + n]);
}

// ---------------- Edge MLP via MFMA (barrier-free, per-wave LDS) ----------------
static __device__ __forceinline__ short8 absdiff8(short8 a, short8 b) {
  short8 r;
#pragma unroll
  for (int j = 0; j < 8; j++) r[j] = (short)f2bf(fabsf(bf2f((ushort)a[j]) - bf2f((ushort)b[j])));
  return r;
}

#define MLP1_STEP(c, e0x, e1x)                                                         \
  {                                                                                    \
    short8 _a0 = (e0x);                                                                \
    short8 _a1 = (e1x);                                                                \
    const uint4* bp = (const uint4*)W1f + (c) * 512 + lane;                            \
    _Pragma("unroll") for (int t = 0; t < 8; t++) {                                    \
      uint4 braw = bp[t * 64];                                                         \
      short8 b = *(short8*)&braw;                                                      \
      acc0[t] = __builtin_amdgcn_mfma_f32_16x16x32_bf16(_a0, b, acc0[t], 0, 0, 0);     \
      acc1[t] = __builtin_amdgcn_mfma_f32_16x16x32_bf16(_a1, b, acc1[t], 0, 0, 0);     \
    }                                                                                  \
  }

__global__ __launch_bounds__(256) void edge_mlp_mfma_kernel(
    const ushort* __restrict__ hb, const int* __restrict__ src, const int* __restrict__ dst,
    const float* __restrict__ eattr, const ushort* __restrict__ W1f,
    const ushort* __restrict__ W2f, const float* __restrict__ bm1,
    const float* __restrict__ bm2, const float* __restrict__ Wm3,
    const float* __restrict__ bm3, float* __restrict__ out) {
  __shared__ ushort t1s[4][16 * 136];  // per-wave private: no barriers needed
  const int tid = threadIdx.x;
  const int w = tid >> 6, lane = tid & 63;
  const int q = lane >> 4, nn = lane & 15;

  float bm1v[8];
#pragma unroll
  for (int t = 0; t < 8; t++) bm1v[t] = bm1[t * 16 + nn];
  float bm2v[4], w3v[4];
#pragma unroll
  for (int t = 0; t < 4; t++) { bm2v[t] = bm2[t * 16 + nn]; w3v[t] = Wm3[t * 16 + nn]; }
  const float bm3v = bm3[0];

  const int base = blockIdx.x * 128 + w * 32;
  const int e0 = base + nn, e1 = base + 16 + nn;
  const int s0 = src[e0], d0 = dst[e0];
  const int s1 = src[e1], d1 = dst[e1];
  const float at0 = eattr[e0], at1 = eattr[e1];

  short8 hs0a = *(const short8*)(hb + s0 * 64 + q * 8);
  short8 hs0b = *(const short8*)(hb + s0 * 64 + 32 + q * 8);
  short8 hd0a = *(const short8*)(hb + d0 * 64 + q * 8);
  short8 hd0b = *(const short8*)(hb + d0 * 64 + 32 + q * 8);
  short8 hs1a = *(const short8*)(hb + s1 * 64 + q * 8);
  short8 hs1b = *(const short8*)(hb + s1 * 64 + 32 + q * 8);
  short8 hd1a = *(const short8*)(hb + d1 * 64 + q * 8);
  short8 hd1b = *(const short8*)(hb + d1 * 64 + 32 + q * 8);

  f32x4 acc0[8], acc1[8];
#pragma unroll
  for (int t = 0; t < 8; t++) {
    acc0[t] = (f32x4){0.f, 0.f, 0.f, 0.f};
    acc1[t] = (f32x4){0.f, 0.f, 0.f, 0.f};
  }

  short8 a6_0 = 0, a6_1 = 0;
  if (q == 0) { a6_0[0] = (short)f2bf(at0); a6_1[0] = (short)f2bf(at1); }

  MLP1_STEP(0, hs0a, hs1a)
  MLP1_STEP(1, hs0b, hs1b)
  MLP1_STEP(2, hd0a, hd1a)
  MLP1_STEP(3, hd0b, hd1b)
  MLP1_STEP(4, absdiff8(hs0a, hd0a), absdiff8(hs1a, hd1a))
  MLP1_STEP(5, absdiff8(hs0b, hd0b), absdiff8(hs1b, hd1b))
  MLP1_STEP(6, a6_0, a6_1)

  ushort* myt1 = t1s[w];
  auto do_group = [&](f32x4* acc, int g) {
#pragma unroll
    for (int t = 0; t < 8; t++)
#pragma unroll
      for (int r = 0; r < 4; r++)
        myt1[(q * 4 + r) * 136 + t * 16 + nn] = f2bf(lrelu(acc[t][r] + bm1v[t]));
    f32x4 acc2[4];
#pragma unroll
    for (int t = 0; t < 4; t++) acc2[t] = (f32x4){0.f, 0.f, 0.f, 0.f};
#pragma unroll
    for (int c2 = 0; c2 < 4; c2++) {
      short8 a = *(short8*)&myt1[nn * 136 + c2 * 32 + q * 8];
#pragma unroll
      for (int t = 0; t < 4; t++) {
        short8 b = *(const short8*)(W2f + ((size_t)(c2 * 4 + t) * 64 + lane) * 8);
        acc2[t] = __builtin_amdgcn_mfma_f32_16x16x32_bf16(a, b, acc2[t], 0, 0, 0);
      }
    }
#pragma unroll
    for (int r = 0; r < 4; r++) {
      float sum = 0.f;
#pragma unroll
      for (int t = 0; t < 4; t++) sum += lrelu(acc2[t][r] + bm2v[t]) * w3v[t];
      sum += __shfl_xor(sum, 1);
      sum += __shfl_xor(sum, 2);
      sum += __shfl_xor(sum, 4);
      sum += __shfl_xor(sum, 8);
      if (nn == 0) out[base + g * 16 + q * 4 + r] = sum + bm3v;
    }
  };
  do_group(acc0, 0);
  do_group(acc1, 1);
}

// ---------------- orchestration ----------------
extern "C" void kernel_launch(void* const* d_in, const int* in_sizes, int n_in,
                              void* d_out, int out_size, void* d_ws, size_t ws_size,
                              hipStream_t stream) {
  const float* x    = (const float*)d_in[0];
  const int*   ei   = (const int*)d_in[1];
  const float* eatt = (const float*)d_in[2];
  const float* W0 = (const float*)d_in[3];
  const float* as0 = (const float*)d_in[4];
  const float* ad0 = (const float*)d_in[5];
  const float* b0 = (const float*)d_in[6];
  const float* W1 = (const float*)d_in[7];
  const float* as1 = (const float*)d_in[8];
  const float* ad1 = (const float*)d_in[9];
  const float* b1 = (const float*)d_in[10];
  const float* W2 = (const float*)d_in[11];
  const float* as2 = (const float*)d_in[12];
  const float* ad2 = (const float*)d_in[13];
  const float* b2 = (const float*)d_in[14];
  const float* g0 = (const float*)d_in[15];
  const float* be0 = (const float*)d_in[16];
  const float* g1 = (const float*)d_in[17];
  const float* be1 = (const float*)d_in[18];
  const float* g2 = (const float*)d_in[19];
  const float* be2 = (const float*)d_in[20];
  const float* Wm1 = (const float*)d_in[21];
  const float* bm1 = (const float*)d_in[22];
  const float* Wm2 = (const float*)d_in[23];
  const float* bm2 = (const float*)d_in[24];
  const float* Wm3 = (const float*)d_in[25];
  const float* bm3 = (const float*)d_in[26];
  const int* src = ei;
  const int* dst = ei + Ee;
  float* out = (float*)d_out;

  // ---- workspace layout (with aliasing; all stream-ordered) ----
  char* w = (char*)d_ws;
  float*  agg  = (float*)w;                                   // Npad*256 fp32 (gather out)
  ushort* xb   = (ushort*)w;                                  // alias: Npad*128 bf16 (layer-0 A)
  ushort* hB   = (ushort*)(w + (size_t)Npad * 256 * 4);       // Npad*256 bf16 (gemm out)
  float*  h2   = (float*)hB;                                  // alias (layer-2 only): Nn*64 fp32
  ushort* aggb = (ushort*)(w + (size_t)Npad * 256 * 6);       // Npad*256 bf16 (post-BN A)
  ushort* hb2  = aggb;                                        // alias: Nn*64 bf16 (edge-MLP feat)
  float*  asrc = (float*)(w + (size_t)Npad * 256 * 8);        // Npad*4
  float*  adst = asrc + (size_t)Npad * 4;                     // Npad*4
  float*  stats = adst + (size_t)Npad * 4;                    // 512
  int* deg      = (int*)(stats + 512);                        // Nn
  int* rowstart = deg + Nn;                                   // Nn+16
  int* cursor   = rowstart + Nn + 16;                         // Nn
  int* elist    = cursor + Nn;                                // Ee+Nn
  ushort* W0f  = (ushort*)(elist + Ee + Nn);                  // 32768
  ushort* W1gf = W0f + 32768;                                 // 65536
  ushort* W2gf = W1gf + 65536;                                // 65536
  ushort* eW1f = W2gf + 65536;                                // 28672
  ushort* eW2f = eW1f + 28672;                                // 8192

  // ---- CSR build (once; edge_index identical for all 3 layers) ----
  filli_kernel<<<(Nn + 255) / 256, 256, 0, stream>>>(deg, 1, Nn);  // self loops
  hist_kernel<<<(Ee + 255) / 256, 256, 0, stream>>>(dst, deg);
  scan_kernel<<<1, 1024, 0, stream>>>(deg, rowstart);
  cursor_init_kernel<<<(Nn + 255) / 256, 256, 0, stream>>>(rowstart, cursor);
  elist_fill_kernel<<<(Ee + Nn + 255) / 256, 256, 0, stream>>>(src, dst, cursor, elist);

  // ---- weight swizzles (once) ----
  wfrag_kernel<<<(32768 + 255) / 256, 256, 0, stream>>>(W0, W0f, FIN);
  wfrag_kernel<<<(65536 + 255) / 256, 256, 0, stream>>>(W1, W1gf, HD);
  wfrag_kernel<<<(65536 + 255) / 256, 256, 0, stream>>>(W2, W2gf, HD);
  w1frag_kernel<<<(7 * 8 * 64 * 8 + 255) / 256, 256, 0, stream>>>(Wm1, eW1f);
  w2frag_kernel<<<(4 * 4 * 64 * 8 + 255) / 256, 256, 0, stream>>>(Wm2, eW2f);

  auto gat = [&](const ushort* Ab, const ushort* Wf, int K, const float* a_s,
                 const float* a_d, const float* bias, bool concat) {
    gemm_mfma_kernel<<<dim3(Npad / 128, 2), 256, 0, stream>>>(Ab, Wf, hB, K, a_s, a_d,
                                                              asrc, adst);
    gat_gather_kernel<<<Nn, 256, 0, stream>>>(elist, rowstart, hB, asrc, adst, bias, agg,
                                              concat ? 1 : 0);
  };

  // Layer 0
  cvt_bf16_kernel<<<(Nn * FIN + 255) / 256, 256, 0, stream>>>(x, xb, Nn * FIN);
  gat(xb, W0f, FIN, as0, ad0, b0, true);
  fill_kernel<<<2, 256, 0, stream>>>(stats, 0.f, 512);
  bn_stats_kernel<<<(Nn + 511) / 512, 256, 0, stream>>>(agg, stats, Nn, HD);
  bn_apply_bf16_kernel<<<(Nn * HD + 255) / 256, 256, 0, stream>>>(agg, stats, g0, be0, aggb, HD, 1);
  // Layer 1
  gat(aggb, W1gf, HD, as1, ad1, b1, true);
  fill_kernel<<<2, 256, 0, stream>>>(stats, 0.f, 512);
  bn_stats_kernel<<<(Nn + 511) / 512, 256, 0, stream>>>(agg, stats, Nn, HD);
  bn_apply_bf16_kernel<<<(Nn * HD + 255) / 256, 256, 0, stream>>>(agg, stats, g1, be1, aggb, HD, 1);
  // Layer 2 (concat=False)
  gat(aggb, W2gf, HD, as2, ad2, b2, false);
  mean_heads_kernel<<<(Nn * HIDd + 255) / 256, 256, 0, stream>>>(agg, b2, h2);
  fill_kernel<<<1, 256, 0, stream>>>(stats, 0.f, 128);
  bn_stats_kernel<<<(Nn + 511) / 512, 256, 0, stream>>>(h2, stats, Nn, HIDd);
  bn_apply_bf16_kernel<<<(Nn * HIDd + 255) / 256, 256, 0, stream>>>(h2, stats, g2, be2, hb2,
                                                                    HIDd, 0);
  // ---- Edge MLP (MFMA bf16) ----
  edge_mlp_mfma_kernel<<<Ee / 128, 256, 0, stream>>>(hb2, src, dst, eatt, eW1f, eW2f, bm1, bm2,
                                                     Wm3, bm3, out);
}